// Round 8
// baseline (467.995 us; speedup 1.0000x reference)
//
#include <hip/hip_runtime.h>
#include <hip/hip_bf16.h>
#include <cstddef>

#define NODES  100000
#define EDGES  3200000
#define ETOT   3300000   // EDGES + NODES self-loops
#define NGRAPH 64
#define HDIM   256
#define BSHIFT 8
#define NBUCK  391       // ceil(NODES / 256)
#define BCAP   10496     // records/bucket: mean 8448 + ~22 sigma

typedef __hip_bfloat16 bf16;
typedef short bf16x8 __attribute__((ext_vector_type(8)));
typedef float f32x4 __attribute__((ext_vector_type(4)));
typedef float f32x2 __attribute__((ext_vector_type(2)));
typedef unsigned u32x2 __attribute__((ext_vector_type(2)));
typedef unsigned u32x4 __attribute__((ext_vector_type(4)));

// ---------------------------------------------------------------- fp32 -> fp8 of x, pre-scaled by dinv[row]
__global__ void xcast_kernel(const float* __restrict__ x, const float* __restrict__ dinv,
                             unsigned char* __restrict__ x8) {
    int i = blockIdx.x * 256 + threadIdx.x;            // 4 elements each
    if ((size_t)i * 4 >= (size_t)NODES * 128) return;
    float d = dinv[i >> 5];                            // 128 cols / 4 = 32 groups per row
    float4 v = *(const float4*)(x + (size_t)i * 4);
    int w = __builtin_amdgcn_cvt_pk_fp8_f32(v.x * d, v.y * d, 0, false);
    w     = __builtin_amdgcn_cvt_pk_fp8_f32(v.z * d, v.w * d, w, true);
    *(unsigned*)(x8 + (size_t)i * 4) = (unsigned)w;
}

// ---------------------------------------------------------------- W1/W2 -> transposed bf16
__global__ void wcast_kernel(const float* __restrict__ W1, const float* __restrict__ W2,
                             bf16* __restrict__ W1t, bf16* __restrict__ W2t) {
    int i = blockIdx.x * 256 + threadIdx.x;
    if (i < 128 * 256) {
        int n = i / 128, k = i - n * 128;
        W1t[i] = __float2bfloat16(W1[(size_t)k * 256 + n]);
    } else if (i < 128 * 256 + 256 * 256) {
        int q = i - 128 * 256;
        int n = q / 256, k = q - n * 256;
        W2t[q] = __float2bfloat16(W2[(size_t)k * 256 + n]);
    }
}

// ---------------------------------------------------------------- fill phase 1: 4-byte bucket records
// rec = (src << 8) | local_dst. 4-copy LDS histogram quarters rank-atomic collisions.
__global__ __launch_bounds__(1024) void fillp1_kernel(const int* __restrict__ row,
                                                      const int* __restrict__ col,
                                                      int* __restrict__ gcnt,
                                                      unsigned* __restrict__ recs) {
    __shared__ int hist[4][NBUCK];
    __shared__ int coff[4][NBUCK];
    __shared__ int base[NBUCK];
    int t  = threadIdx.x;
    int cp = t & 3;
    for (int i = t; i < 4 * NBUCK; i += 1024) ((int*)hist)[i] = 0;
    __syncthreads();
    int e0 = blockIdx.x * 16384;
    int r[16], c[16], rk[16];
    #pragma unroll
    for (int i = 0; i < 16; i++) {
        int e = e0 + i * 1024 + t;
        r[i] = -1;
        if (e < ETOT) {
            if (e < EDGES) { r[i] = row[e]; c[i] = col[e]; }
            else           { r[i] = e - EDGES; c[i] = r[i]; }
            rk[i] = atomicAdd(&hist[cp][c[i] >> BSHIFT], 1);
        }
    }
    __syncthreads();
    for (int b = t; b < NBUCK; b += 1024) {
        int h0 = hist[0][b], h1 = hist[1][b], h2 = hist[2][b], h3 = hist[3][b];
        coff[0][b] = 0; coff[1][b] = h0; coff[2][b] = h0 + h1; coff[3][b] = h0 + h1 + h2;
        int tot = h0 + h1 + h2 + h3;
        base[b] = (tot > 0) ? atomicAdd(&gcnt[b], tot) : 0;
    }
    __syncthreads();
    #pragma unroll
    for (int i = 0; i < 16; i++) {
        if (r[i] >= 0) {
            int b = c[i] >> BSHIFT;
            recs[(size_t)b * BCAP + base[b] + coff[cp][b] + rk[i]] =
                ((unsigned)r[i] << BSHIFT) | (unsigned)(c[i] & 255);
        }
    }
}

// ---------------------------------------------------------------- per-bucket counting sort (256 nodes/bucket)
__global__ __launch_bounds__(256) void build_kernel(const unsigned* __restrict__ recs,
                                                    const int* __restrict__ gcnt,
                                                    int* __restrict__ rowptr,
                                                    float* __restrict__ dinv,
                                                    int* __restrict__ csr) {
    __shared__ int hist[256];
    __shared__ int cur[256];
    __shared__ int part[256];
    __shared__ int sbase;
    const int b = blockIdx.x, t = threadIdx.x;
    const int cnt = gcnt[b];
    const int n0 = b << BSHIFT;
    int pv = (t < b) ? gcnt[t] : 0;
    if (t + 256 < b) pv += gcnt[t + 256];
    part[t] = pv;
    __syncthreads();
    for (int off = 128; off >= 1; off >>= 1) {
        if (t < off) part[t] += part[t + off];
        __syncthreads();
    }
    if (t == 0) sbase = part[0];
    __syncthreads();
    const int base = sbase;
    hist[t] = 0;
    __syncthreads();
    const unsigned* rb = recs + (size_t)b * BCAP;
    for (int i = t; i < cnt; i += 256) atomicAdd(&hist[rb[i] & 255u], 1);
    __syncthreads();
    int h0 = hist[t];
    part[t] = h0;
    __syncthreads();
    for (int off = 1; off < 256; off <<= 1) {
        int v = (t >= off) ? part[t - off] : 0;
        __syncthreads();
        part[t] += v;
        __syncthreads();
    }
    int ex = (t == 0) ? 0 : part[t - 1];       // exclusive over nodes
    cur[t] = ex;
    int v0 = n0 + t;
    if (v0 < NODES) { rowptr[v0] = base + ex; dinv[v0] = rsqrtf((float)h0); }
    if (b == 0 && t == 0) rowptr[NODES] = ETOT;
    __syncthreads();
    for (int i = t; i < cnt; i += 256) {
        unsigned r = rb[i];
        int pos = atomicAdd(&cur[r & 255u], 1);
        csr[base + pos] = (int)(r >> BSHIFT);
    }
}

#define ACC16(q) do {                                                      \
        a[0] += __builtin_amdgcn_cvt_pk_f32_fp8((int)(q).x, false);        \
        a[1] += __builtin_amdgcn_cvt_pk_f32_fp8((int)(q).x, true);         \
        a[2] += __builtin_amdgcn_cvt_pk_f32_fp8((int)(q).y, false);        \
        a[3] += __builtin_amdgcn_cvt_pk_f32_fp8((int)(q).y, true);         \
        a[4] += __builtin_amdgcn_cvt_pk_f32_fp8((int)(q).z, false);        \
        a[5] += __builtin_amdgcn_cvt_pk_f32_fp8((int)(q).z, true);         \
        a[6] += __builtin_amdgcn_cvt_pk_f32_fp8((int)(q).w, false);        \
        a[7] += __builtin_amdgcn_cvt_pk_f32_fp8((int)(q).w, true);         \
    } while (0)

// ---------------------------------------------------------------- fused aggregate + GEMM layer
// Per block: 64 output rows x 256 cols, 512 threads (8 waves).
// Phase 1: aggregate 64 rows of fp8 features (row = K bytes) into LDS
//          (proven agg structure: sub-groups per source, 4-deep gather pipe).
// Phase 2: C = relu(A @ Bt^T + bias) [* dinv if PRESCALE] -> fp8, A decoded
//          from LDS fp8 (proven mgemm structure, 16x16x32 bf16 MFMA).
// MFMA of blocks in phase 2 overlaps other blocks' gather stalls on the CU.
template <int K, bool PRESCALE>
__global__ __launch_bounds__(512, 4) void fused_kernel(const unsigned char* __restrict__ src8,
                                                       const int* __restrict__ rowptr,
                                                       const int* __restrict__ csr,
                                                       const float* __restrict__ dinv,
                                                       const bf16* __restrict__ Bt,
                                                       const float* __restrict__ bias,
                                                       unsigned char* __restrict__ C8) {
    constexpr int ASTR = K + 16;                 // fp8 row stride in LDS (2-way-free reads)
    __shared__ unsigned char As8[64 * ASTR];
    __shared__ short Bs[256][40];                // one 32-k step of Bt, +8 pad
    const int t    = threadIdx.x;
    const int wave = t >> 6;                     // 0..7
    const int lane = t & 63;
    const int bm   = blockIdx.x * 64;

    // ---------------- phase 1: aggregate ----------------
    {
        constexpr int GROUPS = (K == 256) ? 4 : 8;   // source-groups per wave
        constexpr int GL     = 64 / GROUPS;          // lanes per group (16B x GL = K bytes)
        const int sub = lane / GL;
        const int li  = lane % GL;
        for (int nl = wave * 8; nl < wave * 8 + 8; ++nl) {
            int node = bm + nl;
            int beg = 0, end = 0;
            float d = 0.f;
            if (node < NODES) { beg = rowptr[node]; end = rowptr[node + 1]; d = dinv[node]; }
            f32x2 a[8] = {};
            int j = beg;
            int nb = (end - beg) / (GROUPS * 4);
            if (nb > 0) {
                int i0 = csr[j + sub],              i1 = csr[j + GROUPS + sub];
                int i2 = csr[j + 2 * GROUPS + sub], i3 = csr[j + 3 * GROUPS + sub];
                for (int b = 1; b <= nb; ++b) {
                    u32x4 q0 = *(const u32x4*)(src8 + (size_t)i0 * K + li * 16);
                    u32x4 q1 = *(const u32x4*)(src8 + (size_t)i1 * K + li * 16);
                    u32x4 q2 = *(const u32x4*)(src8 + (size_t)i2 * K + li * 16);
                    u32x4 q3 = *(const u32x4*)(src8 + (size_t)i3 * K + li * 16);
                    j += GROUPS * 4;
                    if (b < nb) {
                        i0 = csr[j + sub];              i1 = csr[j + GROUPS + sub];
                        i2 = csr[j + 2 * GROUPS + sub]; i3 = csr[j + 3 * GROUPS + sub];
                    }
                    ACC16(q0); ACC16(q1); ACC16(q2); ACC16(q3);
                }
            }
            for (; j + GROUPS - 1 < end; j += GROUPS) {
                int s = csr[j + sub];
                u32x4 q = *(const u32x4*)(src8 + (size_t)s * K + li * 16);
                ACC16(q);
            }
            if (j + sub < end) {
                int s = csr[j + sub];
                u32x4 q = *(const u32x4*)(src8 + (size_t)s * K + li * 16);
                ACC16(q);
            }
            // reduce across source-groups
            #pragma unroll
            for (int i = 0; i < 8; i++) {
                if (GROUPS == 8) {
                    a[i].x += __shfl_xor(a[i].x, 8, 64);
                    a[i].y += __shfl_xor(a[i].y, 8, 64);
                }
                a[i].x += __shfl_xor(a[i].x, 16, 64);
                a[i].y += __shfl_xor(a[i].y, 16, 64);
                a[i].x += __shfl_xor(a[i].x, 32, 64);
                a[i].y += __shfl_xor(a[i].y, 32, 64);
            }
            if (sub == 0) {
                u32x4 o;
                int p;
                p = __builtin_amdgcn_cvt_pk_fp8_f32(a[0].x * d, a[0].y * d, 0, false);
                p = __builtin_amdgcn_cvt_pk_fp8_f32(a[1].x * d, a[1].y * d, p, true);
                o.x = (unsigned)p;
                p = __builtin_amdgcn_cvt_pk_fp8_f32(a[2].x * d, a[2].y * d, 0, false);
                p = __builtin_amdgcn_cvt_pk_fp8_f32(a[3].x * d, a[3].y * d, p, true);
                o.y = (unsigned)p;
                p = __builtin_amdgcn_cvt_pk_fp8_f32(a[4].x * d, a[4].y * d, 0, false);
                p = __builtin_amdgcn_cvt_pk_fp8_f32(a[5].x * d, a[5].y * d, p, true);
                o.z = (unsigned)p;
                p = __builtin_amdgcn_cvt_pk_fp8_f32(a[6].x * d, a[6].y * d, 0, false);
                p = __builtin_amdgcn_cvt_pk_fp8_f32(a[7].x * d, a[7].y * d, p, true);
                o.w = (unsigned)p;
                *(u32x4*)(As8 + nl * ASTR + li * 16) = o;
            }
        }
    }
    __syncthreads();

    // ---------------- phase 2: GEMM ----------------
    const int m16 = lane & 15, kq = lane >> 4;
    const int wn  = wave * 32;                   // wave's 32-col slice
    f32x4 acc[4][2] = {};
    for (int k0 = 0; k0 < K; k0 += 32) {
        // stage Bs: 256 n-rows x 32 k bf16 = 16 KB, two uint4 per thread
        #pragma unroll
        for (int h = 0; h < 2; h++) {
            int q = t * 2 + h;                   // 0..1023
            int rr = q >> 2, seg = q & 3;
            uint4 vb = *(const uint4*)(Bt + (size_t)rr * K + k0 + seg * 8);
            *(uint4*)&Bs[rr][seg * 8] = vb;
        }
        __syncthreads();
        bf16x8 af[4], bf_[2];
        #pragma unroll
        for (int i = 0; i < 4; i++) {            // decode fp8 -> bf16 fragments
            u32x2 raw = *(const u32x2*)(As8 + (i * 16 + m16) * ASTR + k0 + kq * 8);
            f32x2 d0 = __builtin_amdgcn_cvt_pk_f32_fp8((int)raw.x, false);
            f32x2 d1 = __builtin_amdgcn_cvt_pk_f32_fp8((int)raw.x, true);
            f32x2 d2 = __builtin_amdgcn_cvt_pk_f32_fp8((int)raw.y, false);
            f32x2 d3 = __builtin_amdgcn_cvt_pk_f32_fp8((int)raw.y, true);
            union { __hip_bfloat162 h[4]; bf16x8 v; } pk;
            pk.h[0] = __float22bfloat162_rn(make_float2(d0.x, d0.y));
            pk.h[1] = __float22bfloat162_rn(make_float2(d1.x, d1.y));
            pk.h[2] = __float22bfloat162_rn(make_float2(d2.x, d2.y));
            pk.h[3] = __float22bfloat162_rn(make_float2(d3.x, d3.y));
            af[i] = pk.v;
        }
        #pragma unroll
        for (int i = 0; i < 2; i++)
            bf_[i] = *(const bf16x8*)&Bs[wn + i * 16 + m16][kq * 8];
        #pragma unroll
        for (int mt = 0; mt < 4; mt++)
            #pragma unroll
            for (int nt = 0; nt < 2; nt++)
                acc[mt][nt] = __builtin_amdgcn_mfma_f32_16x16x32_bf16(af[mt], bf_[nt],
                                                                     acc[mt][nt], 0, 0, 0);
        __syncthreads();
    }

    // epilogue: C/D layout col = lane&15, row = (lane>>4)*4 + reg
    #pragma unroll
    for (int mt = 0; mt < 4; mt++) {
        #pragma unroll
        for (int r = 0; r < 4; r++) {
            int row = bm + mt * 16 + kq * 4 + r;
            if (row >= NODES) continue;
            float sc = PRESCALE ? dinv[row] : 1.f;
            #pragma unroll
            for (int nt = 0; nt < 2; nt++) {
                int colb = wn + nt * 16 + m16;
                float v = fmaxf(acc[mt][nt][r] + bias[colb], 0.f) * sc;
                int pkd = __builtin_amdgcn_cvt_pk_fp8_f32(v, v, 0, false);
                C8[(size_t)row * 256 + colb] = (unsigned char)(pkd & 0xff);
            }
        }
    }
}
#undef ACC16

// ---------------------------------------------------------------- segmented mean-pool sum (fp8 in)
__global__ __launch_bounds__(256) void pool_kernel(const unsigned char* __restrict__ h2,
                                                   const int* __restrict__ batch,
                                                   float* __restrict__ sums) {
    int lane = threadIdx.x & 63;                   // 4 cols each
    int wv   = threadIdx.x >> 6;                   // 0..3
    int r0   = blockIdx.x * 128 + wv * 32;
    if (r0 >= NODES) return;
    int r1 = r0 + 32; if (r1 > NODES) r1 = NODES;
    float a0 = 0.f, a1 = 0.f, a2 = 0.f, a3 = 0.f;
    int cb = lane * 4;
    int gfirst = batch[r0], glast = batch[r1 - 1];
    if (gfirst == glast) {
        #pragma unroll 4
        for (int r = r0; r < r1; r++) {
            unsigned q = *(const unsigned*)(h2 + (size_t)r * 256 + cb);
            f32x2 d0 = __builtin_amdgcn_cvt_pk_f32_fp8((int)q, false);
            f32x2 d1 = __builtin_amdgcn_cvt_pk_f32_fp8((int)q, true);
            a0 += d0.x; a1 += d0.y; a2 += d1.x; a3 += d1.y;
        }
        atomicAdd(&sums[gfirst * 256 + cb + 0], a0);
        atomicAdd(&sums[gfirst * 256 + cb + 1], a1);
        atomicAdd(&sums[gfirst * 256 + cb + 2], a2);
        atomicAdd(&sums[gfirst * 256 + cb + 3], a3);
    } else {
        int g = gfirst;
        for (int r = r0; r < r1; r++) {
            int gg = batch[r];
            if (gg != g) {
                atomicAdd(&sums[g * 256 + cb + 0], a0);
                atomicAdd(&sums[g * 256 + cb + 1], a1);
                atomicAdd(&sums[g * 256 + cb + 2], a2);
                atomicAdd(&sums[g * 256 + cb + 3], a3);
                a0 = a1 = a2 = a3 = 0.f; g = gg;
            }
            unsigned q = *(const unsigned*)(h2 + (size_t)r * 256 + cb);
            f32x2 d0 = __builtin_amdgcn_cvt_pk_f32_fp8((int)q, false);
            f32x2 d1 = __builtin_amdgcn_cvt_pk_f32_fp8((int)q, true);
            a0 += d0.x; a1 += d0.y; a2 += d1.x; a3 += d1.y;
        }
        atomicAdd(&sums[g * 256 + cb + 0], a0);
        atomicAdd(&sums[g * 256 + cb + 1], a1);
        atomicAdd(&sums[g * 256 + cb + 2], a2);
        atomicAdd(&sums[g * 256 + cb + 3], a3);
    }
}

// ---------------------------------------------------------------- pooled @ Wl + bl
__global__ void final_kernel(const float* __restrict__ sums, const int* __restrict__ batch,
                             const float* __restrict__ Wl, const float* __restrict__ bl,
                             float* __restrict__ out) {
    int g = blockIdx.x;
    int l = threadIdx.x;
    int lo = 0, hi = NODES;
    while (lo < hi) { int m = (lo + hi) >> 1; if (batch[m] < g) lo = m + 1; else hi = m; }
    int lb = lo;
    lo = lb; hi = NODES;
    while (lo < hi) { int m = (lo + hi) >> 1; if (batch[m] <= g) lo = m + 1; else hi = m; }
    int cnt = lo - lb;
    float inv = 1.f / fmaxf((float)cnt, 1.f);
    float a0 = 0.f, a1 = 0.f;
    for (int k = l; k < 256; k += 64) {
        float p = sums[g * 256 + k] * inv;
        a0 += p * Wl[k * 2 + 0];
        a1 += p * Wl[k * 2 + 1];
    }
    for (int off = 32; off > 0; off >>= 1) {
        a0 += __shfl_down(a0, off, 64);
        a1 += __shfl_down(a1, off, 64);
    }
    if (l == 0) {
        out[g * 2 + 0] = a0 + bl[0];
        out[g * 2 + 1] = a1 + bl[1];
    }
}

// ---------------------------------------------------------------- launch
extern "C" void kernel_launch(void* const* d_in, const int* in_sizes, int n_in,
                              void* d_out, int out_size, void* d_ws, size_t ws_size,
                              hipStream_t stream) {
    const float* x    = (const float*)d_in[0];
    const int*   ei   = (const int*)d_in[1];
    const int*   bat  = (const int*)d_in[2];
    const float* W1   = (const float*)d_in[3];
    const float* b1   = (const float*)d_in[4];
    const float* W2   = (const float*)d_in[5];
    const float* b2   = (const float*)d_in[6];
    const float* Wl   = (const float*)d_in[7];
    const float* bl   = (const float*)d_in[8];
    float*       out  = (float*)d_out;
    const int* erow = ei;           // edge_index[0] = source
    const int* ecol = ei + EDGES;   // edge_index[1] = target

    char* p = (char*)d_ws;
    auto take = [&](size_t bytes) {
        char* r = p;
        p += (bytes + 255) & ~(size_t)255;
        return r;
    };
    float* dinv   = (float*)take((size_t)NODES * 4);
    int*   rowptr = (int*)  take((size_t)(NODES + 1) * 4);
    int*   gcnt   = (int*)  take((size_t)NBUCK * 4);
    int*   csr    = (int*)  take((size_t)ETOT * 4);
    float* sums   = (float*)take((size_t)NGRAPH * HDIM * 4);
    bf16*  W1t    = (bf16*) take((size_t)128 * 256 * 2);
    bf16*  W2t    = (bf16*) take((size_t)256 * 256 * 2);
    char*  reg1   = (char*) take((size_t)NODES * HDIM * 1);   // x8 (12.8)
    char*  reg2   = (char*) take((size_t)NODES * HDIM * 1);   // h1f8 (25.6)
    char*  reg3   = (char*) take((size_t)NODES * HDIM * 1);   // recs (16.4) -> h2f8 (25.6)
    unsigned char* x8      = (unsigned char*)reg1; // dead after fused1
    unsigned char* h1f8    = (unsigned char*)reg2; // born fused1, dead after fused2
    unsigned*      recs    = (unsigned*)reg3;      // dead after build
    unsigned char* h2f8    = (unsigned char*)reg3; // born fused2

    hipMemsetAsync(sums, 0, (size_t)NGRAPH * HDIM * 4, stream);
    hipMemsetAsync(gcnt, 0, (size_t)NBUCK * 4, stream);
    wcast_kernel<<<(128 * 256 + 256 * 256 + 255) / 256, 256, 0, stream>>>(W1, W2, W1t, W2t);

    fillp1_kernel<<<(ETOT + 16383) / 16384, 1024, 0, stream>>>(erow, ecol, gcnt, recs);
    build_kernel <<<NBUCK, 256, 0, stream>>>(recs, gcnt, rowptr, dinv, csr);

    // xcast needs dinv -> after build
    xcast_kernel<<<(NODES * 128 / 4 + 255) / 256, 256, 0, stream>>>(x, dinv, x8);

    const int FB = (NODES + 63) / 64;                 // 1563 blocks of 64 rows
    fused_kernel<128, true ><<<FB, 512, 0, stream>>>(x8,   rowptr, csr, dinv, W1t, b1, h1f8);
    fused_kernel<256, false><<<FB, 512, 0, stream>>>(h1f8, rowptr, csr, dinv, W2t, b2, h2f8);

    pool_kernel<<<(NODES + 127) / 128, 256, 0, stream>>>(h2f8, bat, sums);

    final_kernel<<<NGRAPH, 64, 0, stream>>>(sums, bat, Wl, bl, out);
}

// Round 9
// 443.030 us; speedup vs baseline: 1.0564x; 1.0564x over previous
//
#include <hip/hip_runtime.h>
#include <hip/hip_bf16.h>
#include <cstddef>

#define NODES  100000
#define EDGES  3200000
#define ETOT   3300000   // EDGES + NODES self-loops
#define NGRAPH 64
#define HDIM   256
#define BSHIFT 8
#define NBUCK  391       // ceil(NODES / 256)
#define BCAP   10496     // records/bucket: mean 8448 + ~22 sigma

typedef __hip_bfloat16 bf16;
typedef short bf16x8 __attribute__((ext_vector_type(8)));
typedef float f32x4 __attribute__((ext_vector_type(4)));
typedef float f32x2 __attribute__((ext_vector_type(2)));
typedef unsigned u32x2 __attribute__((ext_vector_type(2)));
typedef unsigned u32x4 __attribute__((ext_vector_type(4)));

// ---------------------------------------------------------------- W1/W2 -> transposed bf16
__global__ void wcast_kernel(const float* __restrict__ W1, const float* __restrict__ W2,
                             bf16* __restrict__ W1t, bf16* __restrict__ W2t) {
    int i = blockIdx.x * 256 + threadIdx.x;
    if (i < 128 * 256) {
        int n = i / 128, k = i - n * 128;
        W1t[i] = __float2bfloat16(W1[(size_t)k * 256 + n]);
    } else if (i < 128 * 256 + 256 * 256) {
        int q = i - 128 * 256;
        int n = q / 256, k = q - n * 256;
        W2t[q] = __float2bfloat16(W2[(size_t)k * 256 + n]);
    }
}

// ---------------------------------------------------------------- fill phase 1: 4-byte bucket records
// rec = (src << 8) | local_dst. 4-copy LDS histogram quarters rank-atomic collisions.
// 8192 edges/block -> 403 blocks: covers all 256 CUs (was 202).
__global__ __launch_bounds__(1024) void fillp1_kernel(const int* __restrict__ row,
                                                      const int* __restrict__ col,
                                                      int* __restrict__ gcnt,
                                                      unsigned* __restrict__ recs) {
    __shared__ int hist[4][NBUCK];
    __shared__ int coff[4][NBUCK];
    __shared__ int base[NBUCK];
    int t  = threadIdx.x;
    int cp = t & 3;
    for (int i = t; i < 4 * NBUCK; i += 1024) ((int*)hist)[i] = 0;
    __syncthreads();
    int e0 = blockIdx.x * 8192;
    int r[8], c[8], rk[8];
    #pragma unroll
    for (int i = 0; i < 8; i++) {
        int e = e0 + i * 1024 + t;
        r[i] = -1;
        if (e < ETOT) {
            if (e < EDGES) { r[i] = row[e]; c[i] = col[e]; }
            else           { r[i] = e - EDGES; c[i] = r[i]; }
            rk[i] = atomicAdd(&hist[cp][c[i] >> BSHIFT], 1);
        }
    }
    __syncthreads();
    for (int b = t; b < NBUCK; b += 1024) {
        int h0 = hist[0][b], h1 = hist[1][b], h2 = hist[2][b], h3 = hist[3][b];
        coff[0][b] = 0; coff[1][b] = h0; coff[2][b] = h0 + h1; coff[3][b] = h0 + h1 + h2;
        int tot = h0 + h1 + h2 + h3;
        base[b] = (tot > 0) ? atomicAdd(&gcnt[b], tot) : 0;
    }
    __syncthreads();
    #pragma unroll
    for (int i = 0; i < 8; i++) {
        if (r[i] >= 0) {
            int b = c[i] >> BSHIFT;
            recs[(size_t)b * BCAP + base[b] + coff[cp][b] + rk[i]] =
                ((unsigned)r[i] << BSHIFT) | (unsigned)(c[i] & 255);
        }
    }
}

// ---------------------------------------------------------------- per-bucket counting sort (256 nodes/bucket)
// + fused xcast tail: this block casts its own 256 x-rows to fp8 (scaled by
//   the dinv values it just computed) -> fills build's idle latency slots and
//   eliminates the separate xcast dispatch.
__global__ __launch_bounds__(256) void build_kernel(const unsigned* __restrict__ recs,
                                                    const int* __restrict__ gcnt,
                                                    int* __restrict__ rowptr,
                                                    float* __restrict__ dinv,
                                                    int* __restrict__ csr,
                                                    const float* __restrict__ x,
                                                    unsigned char* __restrict__ x8) {
    __shared__ int hist[256];
    __shared__ int cur[256];
    __shared__ int part[256];
    __shared__ float dvs[256];
    __shared__ int sbase;
    const int b = blockIdx.x, t = threadIdx.x;
    const int cnt = gcnt[b];
    const int n0 = b << BSHIFT;
    int pv = (t < b) ? gcnt[t] : 0;
    if (t + 256 < b) pv += gcnt[t + 256];
    part[t] = pv;
    __syncthreads();
    for (int off = 128; off >= 1; off >>= 1) {
        if (t < off) part[t] += part[t + off];
        __syncthreads();
    }
    if (t == 0) sbase = part[0];
    __syncthreads();
    const int base = sbase;
    hist[t] = 0;
    __syncthreads();
    const unsigned* rb = recs + (size_t)b * BCAP;
    for (int i = t; i < cnt; i += 256) atomicAdd(&hist[rb[i] & 255u], 1);
    __syncthreads();
    int h0 = hist[t];
    part[t] = h0;
    __syncthreads();
    for (int off = 1; off < 256; off <<= 1) {
        int v = (t >= off) ? part[t - off] : 0;
        __syncthreads();
        part[t] += v;
        __syncthreads();
    }
    int ex = (t == 0) ? 0 : part[t - 1];       // exclusive over nodes
    cur[t] = ex;
    int v0 = n0 + t;
    float dv = rsqrtf((float)h0);
    dvs[t] = dv;
    if (v0 < NODES) { rowptr[v0] = base + ex; dinv[v0] = dv; }
    if (b == 0 && t == 0) rowptr[NODES] = ETOT;
    __syncthreads();
    for (int i = t; i < cnt; i += 256) {
        unsigned r = rb[i];
        int pos = atomicAdd(&cur[r & 255u], 1);
        csr[base + pos] = (int)(r >> BSHIFT);
    }
    // ---- fused xcast: rows n0..n0+255, 32 lanes per row (float4 each) ----
    for (int i = t; i < 256 * 32; i += 256) {
        int rl = i >> 5;                        // local row 0..255
        int node = n0 + rl;
        if (node >= NODES) break;               // rows ascend with i; safe to stop
        float d = dvs[rl];
        float4 v = *(const float4*)(x + (size_t)node * 128 + (i & 31) * 4);
        int w = __builtin_amdgcn_cvt_pk_fp8_f32(v.x * d, v.y * d, 0, false);
        w     = __builtin_amdgcn_cvt_pk_fp8_f32(v.z * d, v.w * d, w, true);
        *(unsigned*)(x8 + (size_t)node * 128 + (i & 31) * 4) = (unsigned)w;
    }
}

#define ACC16(q) do {                                                      \
        a[0] += __builtin_amdgcn_cvt_pk_f32_fp8((int)(q).x, false);        \
        a[1] += __builtin_amdgcn_cvt_pk_f32_fp8((int)(q).x, true);         \
        a[2] += __builtin_amdgcn_cvt_pk_f32_fp8((int)(q).y, false);        \
        a[3] += __builtin_amdgcn_cvt_pk_f32_fp8((int)(q).y, true);         \
        a[4] += __builtin_amdgcn_cvt_pk_f32_fp8((int)(q).z, false);        \
        a[5] += __builtin_amdgcn_cvt_pk_f32_fp8((int)(q).z, true);         \
        a[6] += __builtin_amdgcn_cvt_pk_f32_fp8((int)(q).w, false);        \
        a[7] += __builtin_amdgcn_cvt_pk_f32_fp8((int)(q).w, true);         \
    } while (0)

// ---------------------------------------------------------------- pull aggregation, H=128, fp8 in/out
// One node per wave; 8 lane-groups of 8 lanes; 16B/lane loads (8 lanes x 16B = 128B/row).
__global__ void agg1_kernel(const unsigned char* __restrict__ x8, const int* __restrict__ rowptr,
                            const int* __restrict__ csr, const float* __restrict__ dinv,
                            unsigned char* __restrict__ out) {
    int node = (blockIdx.x * blockDim.x + threadIdx.x) >> 6;
    if (node >= NODES) return;
    int lane = threadIdx.x & 63;
    int sub  = lane >> 3, li = lane & 7;
    int beg = rowptr[node], end = rowptr[node + 1];
    float d = dinv[node];
    f32x2 a[8] = {};
    int j = beg;
    int nb = (end - beg) >> 5;
    if (nb > 0) {
        int i0 = csr[j + sub],      i1 = csr[j + 8 + sub];
        int i2 = csr[j + 16 + sub], i3 = csr[j + 24 + sub];
        for (int b = 1; b <= nb; ++b) {
            u32x4 q0 = *(const u32x4*)(x8 + (size_t)i0 * 128 + li * 16);
            u32x4 q1 = *(const u32x4*)(x8 + (size_t)i1 * 128 + li * 16);
            u32x4 q2 = *(const u32x4*)(x8 + (size_t)i2 * 128 + li * 16);
            u32x4 q3 = *(const u32x4*)(x8 + (size_t)i3 * 128 + li * 16);
            j += 32;
            if (b < nb) {
                i0 = csr[j + sub];      i1 = csr[j + 8 + sub];
                i2 = csr[j + 16 + sub]; i3 = csr[j + 24 + sub];
            }
            ACC16(q0); ACC16(q1); ACC16(q2); ACC16(q3);
        }
    }
    for (; j + 7 < end; j += 8) {
        int s = csr[j + sub];
        u32x4 q = *(const u32x4*)(x8 + (size_t)s * 128 + li * 16);
        ACC16(q);
    }
    if (j + sub < end) {
        int s = csr[j + sub];
        u32x4 q = *(const u32x4*)(x8 + (size_t)s * 128 + li * 16);
        ACC16(q);
    }
    // combine the 8 lane-groups: xor 8, 16, 32
    #pragma unroll
    for (int i = 0; i < 8; i++) {
        a[i].x += __shfl_xor(a[i].x, 8, 64);
        a[i].y += __shfl_xor(a[i].y, 8, 64);
        a[i].x += __shfl_xor(a[i].x, 16, 64);
        a[i].y += __shfl_xor(a[i].y, 16, 64);
        a[i].x += __shfl_xor(a[i].x, 32, 64);
        a[i].y += __shfl_xor(a[i].y, 32, 64);
    }
    if (sub == 0) {
        u32x4 o;
        int p;
        p = __builtin_amdgcn_cvt_pk_fp8_f32(a[0].x * d, a[0].y * d, 0, false);
        p = __builtin_amdgcn_cvt_pk_fp8_f32(a[1].x * d, a[1].y * d, p, true);
        o.x = (unsigned)p;
        p = __builtin_amdgcn_cvt_pk_fp8_f32(a[2].x * d, a[2].y * d, 0, false);
        p = __builtin_amdgcn_cvt_pk_fp8_f32(a[3].x * d, a[3].y * d, p, true);
        o.y = (unsigned)p;
        p = __builtin_amdgcn_cvt_pk_fp8_f32(a[4].x * d, a[4].y * d, 0, false);
        p = __builtin_amdgcn_cvt_pk_fp8_f32(a[5].x * d, a[5].y * d, p, true);
        o.z = (unsigned)p;
        p = __builtin_amdgcn_cvt_pk_fp8_f32(a[6].x * d, a[6].y * d, 0, false);
        p = __builtin_amdgcn_cvt_pk_fp8_f32(a[7].x * d, a[7].y * d, p, true);
        o.w = (unsigned)p;
        *(u32x4*)(out + (size_t)node * 128 + li * 16) = o;
    }
}

// ---------------------------------------------------------------- pull aggregation, H=256, fp8 in/out
// One node per wave; 4 lane-groups of 16 lanes; 16B/lane loads (16 lanes x 16B = 256B/row).
__global__ void agg2_kernel(const unsigned char* __restrict__ h8, const int* __restrict__ rowptr,
                            const int* __restrict__ csr, const float* __restrict__ dinv,
                            unsigned char* __restrict__ out) {
    int node = (blockIdx.x * blockDim.x + threadIdx.x) >> 6;
    if (node >= NODES) return;
    int lane = threadIdx.x & 63;
    int sub  = lane >> 4, li = lane & 15;
    int beg = rowptr[node], end = rowptr[node + 1];
    float d = dinv[node];
    f32x2 a[8] = {};
    int j = beg;
    int nb = (end - beg) >> 4;
    if (nb > 0) {
        int i0 = csr[j + sub],     i1 = csr[j + 4 + sub];
        int i2 = csr[j + 8 + sub], i3 = csr[j + 12 + sub];
        for (int b = 1; b <= nb; ++b) {
            u32x4 q0 = *(const u32x4*)(h8 + (size_t)i0 * 256 + li * 16);
            u32x4 q1 = *(const u32x4*)(h8 + (size_t)i1 * 256 + li * 16);
            u32x4 q2 = *(const u32x4*)(h8 + (size_t)i2 * 256 + li * 16);
            u32x4 q3 = *(const u32x4*)(h8 + (size_t)i3 * 256 + li * 16);
            j += 16;
            if (b < nb) {
                i0 = csr[j + sub];     i1 = csr[j + 4 + sub];
                i2 = csr[j + 8 + sub]; i3 = csr[j + 12 + sub];
            }
            ACC16(q0); ACC16(q1); ACC16(q2); ACC16(q3);
        }
    }
    for (; j + 3 < end; j += 4) {
        int s = csr[j + sub];
        u32x4 q = *(const u32x4*)(h8 + (size_t)s * 256 + li * 16);
        ACC16(q);
    }
    if (j + sub < end) {
        int s = csr[j + sub];
        u32x4 q = *(const u32x4*)(h8 + (size_t)s * 256 + li * 16);
        ACC16(q);
    }
    // combine the 4 lane-groups: xor 16, 32
    #pragma unroll
    for (int i = 0; i < 8; i++) {
        a[i].x += __shfl_xor(a[i].x, 16, 64);
        a[i].y += __shfl_xor(a[i].y, 16, 64);
        a[i].x += __shfl_xor(a[i].x, 32, 64);
        a[i].y += __shfl_xor(a[i].y, 32, 64);
    }
    if (sub == 0) {
        u32x4 o;
        int p;
        p = __builtin_amdgcn_cvt_pk_fp8_f32(a[0].x * d, a[0].y * d, 0, false);
        p = __builtin_amdgcn_cvt_pk_fp8_f32(a[1].x * d, a[1].y * d, p, true);
        o.x = (unsigned)p;
        p = __builtin_amdgcn_cvt_pk_fp8_f32(a[2].x * d, a[2].y * d, 0, false);
        p = __builtin_amdgcn_cvt_pk_fp8_f32(a[3].x * d, a[3].y * d, p, true);
        o.y = (unsigned)p;
        p = __builtin_amdgcn_cvt_pk_fp8_f32(a[4].x * d, a[4].y * d, 0, false);
        p = __builtin_amdgcn_cvt_pk_fp8_f32(a[5].x * d, a[5].y * d, p, true);
        o.z = (unsigned)p;
        p = __builtin_amdgcn_cvt_pk_fp8_f32(a[6].x * d, a[6].y * d, 0, false);
        p = __builtin_amdgcn_cvt_pk_fp8_f32(a[7].x * d, a[7].y * d, p, true);
        o.w = (unsigned)p;
        *(u32x4*)(out + (size_t)node * 256 + li * 16) = o;
    }
}
#undef ACC16

// ---------------------------------------------------------------- MFMA GEMM 128x128, fp8 A (decoded), bf16 B
// C[M,256] = relu(A8[M,K] @ B[K,256] + bias) [* dinv[row] if PRESCALE], written fp8 e4m3.
template <int K, bool PRESCALE>
__global__ __launch_bounds__(256) void mgemm_kernel(const unsigned char* __restrict__ A8,
                                                    const bf16* __restrict__ Bt,
                                                    const float* __restrict__ bias,
                                                    const float* __restrict__ dinv,
                                                    unsigned char* __restrict__ C8) {
    __shared__ short As[128][40];   // [m][k] bf16 (decoded from fp8), +8 pad
    __shared__ short Bs[128][40];   // [n][k] bf16
    const int t    = threadIdx.x;
    const int bm   = (int)(blockIdx.x >> 1) * 128;
    const int bn   = (int)(blockIdx.x & 1) * 128;
    const int lane = t & 63;
    const int wave = t >> 6;
    const int wm   = (wave >> 1) * 64, wn = (wave & 1) * 64;
    const int m16  = lane & 15, kq = lane >> 4;
    f32x4 acc[4][4] = {};

    for (int k0 = 0; k0 < K; k0 += 32) {
        // A tile: 128 rows x 32 fp8 = 4 KB, one uint4 (16 fp8) per thread, decode -> bf16 LDS
        {
            int rr = t >> 1, seg = t & 1;          // seg*16 fp8 within the 32-k tile
            uint4 va = {0u, 0u, 0u, 0u};
            int grow = bm + rr;
            if (grow < NODES) va = *(const uint4*)(A8 + (size_t)grow * K + k0 + seg * 16);
            unsigned wd[4] = {va.x, va.y, va.z, va.w};
            #pragma unroll
            for (int u = 0; u < 4; u++) {
                f32x2 lo = __builtin_amdgcn_cvt_pk_f32_fp8((int)wd[u], false);
                f32x2 hi = __builtin_amdgcn_cvt_pk_f32_fp8((int)wd[u], true);
                union { __hip_bfloat162 h[2]; u32x2 q; } pk;
                pk.h[0] = __float22bfloat162_rn(make_float2(lo.x, lo.y));
                pk.h[1] = __float22bfloat162_rn(make_float2(hi.x, hi.y));
                *(u32x2*)&As[rr][seg * 16 + u * 4] = pk.q;
            }
        }
        // B tile: 128 n-rows x 32 k bf16 = 8 KB, two uint4 per thread
        #pragma unroll
        for (int h = 0; h < 2; h++) {
            int q = t * 2 + h;
            int rr = q >> 2, seg = q & 3;
            uint4 vb = *(const uint4*)(Bt + (size_t)(bn + rr) * K + k0 + seg * 8);
            *(uint4*)&Bs[rr][seg * 8] = vb;
        }
        __syncthreads();
        bf16x8 af[4], bf_[4];
        #pragma unroll
        for (int i = 0; i < 4; i++) {
            af[i]  = *(const bf16x8*)&As[wm + i * 16 + m16][kq * 8];
            bf_[i] = *(const bf16x8*)&Bs[wn + i * 16 + m16][kq * 8];
        }
        #pragma unroll
        for (int mt = 0; mt < 4; mt++)
            #pragma unroll
            for (int nt = 0; nt < 4; nt++)
                acc[mt][nt] = __builtin_amdgcn_mfma_f32_16x16x32_bf16(af[mt], bf_[nt],
                                                                     acc[mt][nt], 0, 0, 0);
        __syncthreads();
    }

    // C/D layout: col = lane&15, row = (lane>>4)*4 + reg
    #pragma unroll
    for (int mt = 0; mt < 4; mt++) {
        #pragma unroll
        for (int r = 0; r < 4; r++) {
            int row = bm + wm + mt * 16 + kq * 4 + r;
            if (row >= NODES) continue;
            float sc = PRESCALE ? dinv[row] : 1.f;
            #pragma unroll
            for (int nt = 0; nt < 4; nt++) {
                int colb = bn + wn + nt * 16 + m16;
                float v = fmaxf(acc[mt][nt][r] + bias[colb], 0.f) * sc;
                int pkd = __builtin_amdgcn_cvt_pk_fp8_f32(v, v, 0, false);
                C8[(size_t)row * 256 + colb] = (unsigned char)(pkd & 0xff);
            }
        }
    }
}

// ---------------------------------------------------------------- segmented mean-pool sum (fp8 in)
// 128 rows/block, 32 rows/wave; lane covers 4 cols. Fast path when the wave's
// whole row-range is one graph (~98% of waves): branch-free unrolled loop.
__global__ __launch_bounds__(256) void pool_kernel(const unsigned char* __restrict__ h2,
                                                   const int* __restrict__ batch,
                                                   float* __restrict__ sums) {
    int lane = threadIdx.x & 63;                   // 4 cols each
    int wv   = threadIdx.x >> 6;                   // 0..3
    int r0   = blockIdx.x * 128 + wv * 32;
    if (r0 >= NODES) return;
    int r1 = r0 + 32; if (r1 > NODES) r1 = NODES;
    float a0 = 0.f, a1 = 0.f, a2 = 0.f, a3 = 0.f;
    int cb = lane * 4;
    int gfirst = batch[r0], glast = batch[r1 - 1];
    if (gfirst == glast) {
        #pragma unroll 4
        for (int r = r0; r < r1; r++) {
            unsigned q = *(const unsigned*)(h2 + (size_t)r * 256 + cb);
            f32x2 d0 = __builtin_amdgcn_cvt_pk_f32_fp8((int)q, false);
            f32x2 d1 = __builtin_amdgcn_cvt_pk_f32_fp8((int)q, true);
            a0 += d0.x; a1 += d0.y; a2 += d1.x; a3 += d1.y;
        }
        atomicAdd(&sums[gfirst * 256 + cb + 0], a0);
        atomicAdd(&sums[gfirst * 256 + cb + 1], a1);
        atomicAdd(&sums[gfirst * 256 + cb + 2], a2);
        atomicAdd(&sums[gfirst * 256 + cb + 3], a3);
    } else {
        int g = gfirst;
        for (int r = r0; r < r1; r++) {
            int gg = batch[r];
            if (gg != g) {
                atomicAdd(&sums[g * 256 + cb + 0], a0);
                atomicAdd(&sums[g * 256 + cb + 1], a1);
                atomicAdd(&sums[g * 256 + cb + 2], a2);
                atomicAdd(&sums[g * 256 + cb + 3], a3);
                a0 = a1 = a2 = a3 = 0.f; g = gg;
            }
            unsigned q = *(const unsigned*)(h2 + (size_t)r * 256 + cb);
            f32x2 d0 = __builtin_amdgcn_cvt_pk_f32_fp8((int)q, false);
            f32x2 d1 = __builtin_amdgcn_cvt_pk_f32_fp8((int)q, true);
            a0 += d0.x; a1 += d0.y; a2 += d1.x; a3 += d1.y;
        }
        atomicAdd(&sums[g * 256 + cb + 0], a0);
        atomicAdd(&sums[g * 256 + cb + 1], a1);
        atomicAdd(&sums[g * 256 + cb + 2], a2);
        atomicAdd(&sums[g * 256 + cb + 3], a3);
    }
}

// ---------------------------------------------------------------- pooled @ Wl + bl
__global__ void final_kernel(const float* __restrict__ sums, const int* __restrict__ batch,
                             const float* __restrict__ Wl, const float* __restrict__ bl,
                             float* __restrict__ out) {
    int g = blockIdx.x;
    int l = threadIdx.x;
    int lo = 0, hi = NODES;
    while (lo < hi) { int m = (lo + hi) >> 1; if (batch[m] < g) lo = m + 1; else hi = m; }
    int lb = lo;
    lo = lb; hi = NODES;
    while (lo < hi) { int m = (lo + hi) >> 1; if (batch[m] <= g) lo = m + 1; else hi = m; }
    int cnt = lo - lb;
    float inv = 1.f / fmaxf((float)cnt, 1.f);
    float a0 = 0.f, a1 = 0.f;
    for (int k = l; k < 256; k += 64) {
        float p = sums[g * 256 + k] * inv;
        a0 += p * Wl[k * 2 + 0];
        a1 += p * Wl[k * 2 + 1];
    }
    for (int off = 32; off > 0; off >>= 1) {
        a0 += __shfl_down(a0, off, 64);
        a1 += __shfl_down(a1, off, 64);
    }
    if (l == 0) {
        out[g * 2 + 0] = a0 + bl[0];
        out[g * 2 + 1] = a1 + bl[1];
    }
}

// ---------------------------------------------------------------- launch
extern "C" void kernel_launch(void* const* d_in, const int* in_sizes, int n_in,
                              void* d_out, int out_size, void* d_ws, size_t ws_size,
                              hipStream_t stream) {
    const float* x    = (const float*)d_in[0];
    const int*   ei   = (const int*)d_in[1];
    const int*   bat  = (const int*)d_in[2];
    const float* W1   = (const float*)d_in[3];
    const float* b1   = (const float*)d_in[4];
    const float* W2   = (const float*)d_in[5];
    const float* b2   = (const float*)d_in[6];
    const float* Wl   = (const float*)d_in[7];
    const float* bl   = (const float*)d_in[8];
    float*       out  = (float*)d_out;
    const int* erow = ei;           // edge_index[0] = source
    const int* ecol = ei + EDGES;   // edge_index[1] = target

    char* p = (char*)d_ws;
    auto take = [&](size_t bytes) {
        char* r = p;
        p += (bytes + 255) & ~(size_t)255;
        return r;
    };
    float* dinv   = (float*)take((size_t)NODES * 4);
    int*   rowptr = (int*)  take((size_t)(NODES + 1) * 4);
    int*   gcnt   = (int*)  take((size_t)NBUCK * 4);
    int*   csr    = (int*)  take((size_t)ETOT * 4);
    float* sums   = (float*)take((size_t)NGRAPH * HDIM * 4);
    bf16*  W1t    = (bf16*) take((size_t)128 * 256 * 2);
    bf16*  W2t    = (bf16*) take((size_t)256 * 256 * 2);
    char*  reg1   = (char*) take((size_t)NODES * HDIM * 1);   // x8 (12.8) -> h1f8 (25.6)
    char*  reg2   = (char*) take((size_t)NODES * HDIM * 1);   // aggbuf1 (12.8) -> aggbuf2 (25.6)
    char*  reg3   = (char*) take((size_t)NODES * HDIM * 1);   // recs (16.4) -> h2f8 (25.6)
    unsigned char* x8      = (unsigned char*)reg1; // dead after agg1
    unsigned char* h1f8    = (unsigned char*)reg1; // born mgemm1, dead after agg2
    unsigned char* aggbuf1 = (unsigned char*)reg2; // born agg1, dead after mgemm1
    unsigned char* aggbuf2 = (unsigned char*)reg2; // born agg2, dead after mgemm2
    unsigned*      recs    = (unsigned*)reg3;      // dead after build
    unsigned char* h2f8    = (unsigned char*)reg3; // born mgemm2

    hipMemsetAsync(sums, 0, (size_t)NGRAPH * HDIM * 4, stream);
    hipMemsetAsync(gcnt, 0, (size_t)NBUCK * 4, stream);
    wcast_kernel<<<(128 * 256 + 256 * 256 + 255) / 256, 256, 0, stream>>>(W1, W2, W1t, W2t);

    fillp1_kernel<<<(ETOT + 8191) / 8192, 1024, 0, stream>>>(erow, ecol, gcnt, recs);
    // build computes rowptr/dinv/csr AND casts x -> x8 (fused xcast)
    build_kernel <<<NBUCK, 256, 0, stream>>>(recs, gcnt, rowptr, dinv, csr, x, x8);

    const int AGG_BLOCKS = ((size_t)NODES * 64 + 255) / 256;  // 1 node per wave
    agg1_kernel<<<AGG_BLOCKS, 256, 0, stream>>>(x8, rowptr, csr, dinv, aggbuf1);

    const int MB = (NODES + 127) / 128;               // 782
    mgemm_kernel<128, true ><<<MB * 2, 256, 0, stream>>>(aggbuf1, W1t, b1, dinv, h1f8);

    agg2_kernel<<<AGG_BLOCKS, 256, 0, stream>>>(h1f8, rowptr, csr, dinv, aggbuf2);

    mgemm_kernel<256, false><<<MB * 2, 256, 0, stream>>>(aggbuf2, W2t, b2, nullptr, h2f8);

    pool_kernel<<<(NODES + 127) / 128, 256, 0, stream>>>(h2f8, bat, sums);

    final_kernel<<<NGRAPH, 64, 0, stream>>>(sums, bat, Wl, bl, out);
}

// Round 10
// 439.670 us; speedup vs baseline: 1.0644x; 1.0076x over previous
//
#include <hip/hip_runtime.h>
#include <hip/hip_bf16.h>
#include <cstddef>

#define NODES  100000
#define EDGES  3200000
#define ETOT   3300000   // EDGES + NODES self-loops
#define NGRAPH 64
#define HDIM   256
#define BSHIFT 8
#define NBUCK  391       // ceil(NODES / 256)
#define BCAP   10496     // records/bucket: mean 8448 + ~22 sigma

typedef __hip_bfloat16 bf16;
typedef short bf16x8 __attribute__((ext_vector_type(8)));
typedef float f32x4 __attribute__((ext_vector_type(4)));
typedef float f32x2 __attribute__((ext_vector_type(2)));
typedef unsigned u32x2 __attribute__((ext_vector_type(2)));
typedef unsigned u32x4 __attribute__((ext_vector_type(4)));

// ---------------------------------------------------------------- fp32 -> fp8 of x, pre-scaled by dinv[row]
__global__ void xcast_kernel(const float* __restrict__ x, const float* __restrict__ dinv,
                             unsigned char* __restrict__ x8) {
    int i = blockIdx.x * 256 + threadIdx.x;            // 4 elements each
    if ((size_t)i * 4 >= (size_t)NODES * 128) return;
    float d = dinv[i >> 5];                            // 128 cols / 4 = 32 groups per row
    float4 v = *(const float4*)(x + (size_t)i * 4);
    int w = __builtin_amdgcn_cvt_pk_fp8_f32(v.x * d, v.y * d, 0, false);
    w     = __builtin_amdgcn_cvt_pk_fp8_f32(v.z * d, v.w * d, w, true);
    *(unsigned*)(x8 + (size_t)i * 4) = (unsigned)w;
}

// ---------------------------------------------------------------- W1/W2 -> transposed bf16
__global__ void wcast_kernel(const float* __restrict__ W1, const float* __restrict__ W2,
                             bf16* __restrict__ W1t, bf16* __restrict__ W2t) {
    int i = blockIdx.x * 256 + threadIdx.x;
    if (i < 128 * 256) {
        int n = i / 128, k = i - n * 128;
        W1t[i] = __float2bfloat16(W1[(size_t)k * 256 + n]);
    } else if (i < 128 * 256 + 256 * 256) {
        int q = i - 128 * 256;
        int n = q / 256, k = q - n * 256;
        W2t[q] = __float2bfloat16(W2[(size_t)k * 256 + n]);
    }
}

// ---------------------------------------------------------------- fill phase 1: 4-byte bucket records
// rec = (src << 8) | local_dst. 4-copy LDS histogram quarters rank-atomic collisions.
// 8192 edges/block -> 403 blocks: covers all 256 CUs.
__global__ __launch_bounds__(1024) void fillp1_kernel(const int* __restrict__ row,
                                                      const int* __restrict__ col,
                                                      int* __restrict__ gcnt,
                                                      unsigned* __restrict__ recs) {
    __shared__ int hist[4][NBUCK];
    __shared__ int coff[4][NBUCK];
    __shared__ int base[NBUCK];
    int t  = threadIdx.x;
    int cp = t & 3;
    for (int i = t; i < 4 * NBUCK; i += 1024) ((int*)hist)[i] = 0;
    __syncthreads();
    int e0 = blockIdx.x * 8192;
    int r[8], c[8], rk[8];
    #pragma unroll
    for (int i = 0; i < 8; i++) {
        int e = e0 + i * 1024 + t;
        r[i] = -1;
        if (e < ETOT) {
            if (e < EDGES) { r[i] = row[e]; c[i] = col[e]; }
            else           { r[i] = e - EDGES; c[i] = r[i]; }
            rk[i] = atomicAdd(&hist[cp][c[i] >> BSHIFT], 1);
        }
    }
    __syncthreads();
    for (int b = t; b < NBUCK; b += 1024) {
        int h0 = hist[0][b], h1 = hist[1][b], h2 = hist[2][b], h3 = hist[3][b];
        coff[0][b] = 0; coff[1][b] = h0; coff[2][b] = h0 + h1; coff[3][b] = h0 + h1 + h2;
        int tot = h0 + h1 + h2 + h3;
        base[b] = (tot > 0) ? atomicAdd(&gcnt[b], tot) : 0;
    }
    __syncthreads();
    #pragma unroll
    for (int i = 0; i < 8; i++) {
        if (r[i] >= 0) {
            int b = c[i] >> BSHIFT;
            recs[(size_t)b * BCAP + base[b] + coff[cp][b] + rk[i]] =
                ((unsigned)r[i] << BSHIFT) | (unsigned)(c[i] & 255);
        }
    }
}

// ---------------------------------------------------------------- per-bucket counting sort (256 nodes/bucket)
__global__ __launch_bounds__(256) void build_kernel(const unsigned* __restrict__ recs,
                                                    const int* __restrict__ gcnt,
                                                    int* __restrict__ rowptr,
                                                    float* __restrict__ dinv,
                                                    int* __restrict__ csr) {
    __shared__ int hist[256];
    __shared__ int cur[256];
    __shared__ int part[256];
    __shared__ int sbase;
    const int b = blockIdx.x, t = threadIdx.x;
    const int cnt = gcnt[b];
    const int n0 = b << BSHIFT;
    int pv = (t < b) ? gcnt[t] : 0;
    if (t + 256 < b) pv += gcnt[t + 256];
    part[t] = pv;
    __syncthreads();
    for (int off = 128; off >= 1; off >>= 1) {
        if (t < off) part[t] += part[t + off];
        __syncthreads();
    }
    if (t == 0) sbase = part[0];
    __syncthreads();
    const int base = sbase;
    hist[t] = 0;
    __syncthreads();
    const unsigned* rb = recs + (size_t)b * BCAP;
    for (int i = t; i < cnt; i += 256) atomicAdd(&hist[rb[i] & 255u], 1);
    __syncthreads();
    int h0 = hist[t];
    part[t] = h0;
    __syncthreads();
    for (int off = 1; off < 256; off <<= 1) {
        int v = (t >= off) ? part[t - off] : 0;
        __syncthreads();
        part[t] += v;
        __syncthreads();
    }
    int ex = (t == 0) ? 0 : part[t - 1];       // exclusive over nodes
    cur[t] = ex;
    int v0 = n0 + t;
    if (v0 < NODES) { rowptr[v0] = base + ex; dinv[v0] = rsqrtf((float)h0); }
    if (b == 0 && t == 0) rowptr[NODES] = ETOT;
    __syncthreads();
    for (int i = t; i < cnt; i += 256) {
        unsigned r = rb[i];
        int pos = atomicAdd(&cur[r & 255u], 1);
        csr[base + pos] = (int)(r >> BSHIFT);
    }
}

#define ACC16(q) do {                                                      \
        a[0] += __builtin_amdgcn_cvt_pk_f32_fp8((int)(q).x, false);        \
        a[1] += __builtin_amdgcn_cvt_pk_f32_fp8((int)(q).x, true);         \
        a[2] += __builtin_amdgcn_cvt_pk_f32_fp8((int)(q).y, false);        \
        a[3] += __builtin_amdgcn_cvt_pk_f32_fp8((int)(q).y, true);         \
        a[4] += __builtin_amdgcn_cvt_pk_f32_fp8((int)(q).z, false);        \
        a[5] += __builtin_amdgcn_cvt_pk_f32_fp8((int)(q).z, true);         \
        a[6] += __builtin_amdgcn_cvt_pk_f32_fp8((int)(q).w, false);        \
        a[7] += __builtin_amdgcn_cvt_pk_f32_fp8((int)(q).w, true);         \
    } while (0)

// ---------------------------------------------------------------- pull aggregation, H=128, fp8 in/out
// One node per wave; 8 lane-groups of 8 lanes; 16B/lane loads (8 lanes x 16B = 128B/row).
__global__ void agg1_kernel(const unsigned char* __restrict__ x8, const int* __restrict__ rowptr,
                            const int* __restrict__ csr, const float* __restrict__ dinv,
                            unsigned char* __restrict__ out) {
    int node = (blockIdx.x * blockDim.x + threadIdx.x) >> 6;
    if (node >= NODES) return;
    int lane = threadIdx.x & 63;
    int sub  = lane >> 3, li = lane & 7;
    int beg = rowptr[node], end = rowptr[node + 1];
    float d = dinv[node];
    f32x2 a[8] = {};
    int j = beg;
    int nb = (end - beg) >> 5;
    if (nb > 0) {
        int i0 = csr[j + sub],      i1 = csr[j + 8 + sub];
        int i2 = csr[j + 16 + sub], i3 = csr[j + 24 + sub];
        for (int b = 1; b <= nb; ++b) {
            u32x4 q0 = *(const u32x4*)(x8 + (size_t)i0 * 128 + li * 16);
            u32x4 q1 = *(const u32x4*)(x8 + (size_t)i1 * 128 + li * 16);
            u32x4 q2 = *(const u32x4*)(x8 + (size_t)i2 * 128 + li * 16);
            u32x4 q3 = *(const u32x4*)(x8 + (size_t)i3 * 128 + li * 16);
            j += 32;
            if (b < nb) {
                i0 = csr[j + sub];      i1 = csr[j + 8 + sub];
                i2 = csr[j + 16 + sub]; i3 = csr[j + 24 + sub];
            }
            ACC16(q0); ACC16(q1); ACC16(q2); ACC16(q3);
        }
    }
    for (; j + 7 < end; j += 8) {
        int s = csr[j + sub];
        u32x4 q = *(const u32x4*)(x8 + (size_t)s * 128 + li * 16);
        ACC16(q);
    }
    if (j + sub < end) {
        int s = csr[j + sub];
        u32x4 q = *(const u32x4*)(x8 + (size_t)s * 128 + li * 16);
        ACC16(q);
    }
    // combine the 8 lane-groups: xor 8, 16, 32
    #pragma unroll
    for (int i = 0; i < 8; i++) {
        a[i].x += __shfl_xor(a[i].x, 8, 64);
        a[i].y += __shfl_xor(a[i].y, 8, 64);
        a[i].x += __shfl_xor(a[i].x, 16, 64);
        a[i].y += __shfl_xor(a[i].y, 16, 64);
        a[i].x += __shfl_xor(a[i].x, 32, 64);
        a[i].y += __shfl_xor(a[i].y, 32, 64);
    }
    if (sub == 0) {
        u32x4 o;
        int p;
        p = __builtin_amdgcn_cvt_pk_fp8_f32(a[0].x * d, a[0].y * d, 0, false);
        p = __builtin_amdgcn_cvt_pk_fp8_f32(a[1].x * d, a[1].y * d, p, true);
        o.x = (unsigned)p;
        p = __builtin_amdgcn_cvt_pk_fp8_f32(a[2].x * d, a[2].y * d, 0, false);
        p = __builtin_amdgcn_cvt_pk_fp8_f32(a[3].x * d, a[3].y * d, p, true);
        o.y = (unsigned)p;
        p = __builtin_amdgcn_cvt_pk_fp8_f32(a[4].x * d, a[4].y * d, 0, false);
        p = __builtin_amdgcn_cvt_pk_fp8_f32(a[5].x * d, a[5].y * d, p, true);
        o.z = (unsigned)p;
        p = __builtin_amdgcn_cvt_pk_fp8_f32(a[6].x * d, a[6].y * d, 0, false);
        p = __builtin_amdgcn_cvt_pk_fp8_f32(a[7].x * d, a[7].y * d, p, true);
        o.w = (unsigned)p;
        *(u32x4*)(out + (size_t)node * 128 + li * 16) = o;
    }
}

// ---------------------------------------------------------------- pull aggregation, H=256, fp8 in/out
// One node per wave; 4 lane-groups of 16 lanes; 16B/lane loads (16 lanes x 16B = 256B/row).
__global__ void agg2_kernel(const unsigned char* __restrict__ h8, const int* __restrict__ rowptr,
                            const int* __restrict__ csr, const float* __restrict__ dinv,
                            unsigned char* __restrict__ out) {
    int node = (blockIdx.x * blockDim.x + threadIdx.x) >> 6;
    if (node >= NODES) return;
    int lane = threadIdx.x & 63;
    int sub  = lane >> 4, li = lane & 15;
    int beg = rowptr[node], end = rowptr[node + 1];
    float d = dinv[node];
    f32x2 a[8] = {};
    int j = beg;
    int nb = (end - beg) >> 4;
    if (nb > 0) {
        int i0 = csr[j + sub],     i1 = csr[j + 4 + sub];
        int i2 = csr[j + 8 + sub], i3 = csr[j + 12 + sub];
        for (int b = 1; b <= nb; ++b) {
            u32x4 q0 = *(const u32x4*)(h8 + (size_t)i0 * 256 + li * 16);
            u32x4 q1 = *(const u32x4*)(h8 + (size_t)i1 * 256 + li * 16);
            u32x4 q2 = *(const u32x4*)(h8 + (size_t)i2 * 256 + li * 16);
            u32x4 q3 = *(const u32x4*)(h8 + (size_t)i3 * 256 + li * 16);
            j += 16;
            if (b < nb) {
                i0 = csr[j + sub];     i1 = csr[j + 4 + sub];
                i2 = csr[j + 8 + sub]; i3 = csr[j + 12 + sub];
            }
            ACC16(q0); ACC16(q1); ACC16(q2); ACC16(q3);
        }
    }
    for (; j + 3 < end; j += 4) {
        int s = csr[j + sub];
        u32x4 q = *(const u32x4*)(h8 + (size_t)s * 256 + li * 16);
        ACC16(q);
    }
    if (j + sub < end) {
        int s = csr[j + sub];
        u32x4 q = *(const u32x4*)(h8 + (size_t)s * 256 + li * 16);
        ACC16(q);
    }
    // combine the 4 lane-groups: xor 16, 32
    #pragma unroll
    for (int i = 0; i < 8; i++) {
        a[i].x += __shfl_xor(a[i].x, 16, 64);
        a[i].y += __shfl_xor(a[i].y, 16, 64);
        a[i].x += __shfl_xor(a[i].x, 32, 64);
        a[i].y += __shfl_xor(a[i].y, 32, 64);
    }
    if (sub == 0) {
        u32x4 o;
        int p;
        p = __builtin_amdgcn_cvt_pk_fp8_f32(a[0].x * d, a[0].y * d, 0, false);
        p = __builtin_amdgcn_cvt_pk_fp8_f32(a[1].x * d, a[1].y * d, p, true);
        o.x = (unsigned)p;
        p = __builtin_amdgcn_cvt_pk_fp8_f32(a[2].x * d, a[2].y * d, 0, false);
        p = __builtin_amdgcn_cvt_pk_fp8_f32(a[3].x * d, a[3].y * d, p, true);
        o.y = (unsigned)p;
        p = __builtin_amdgcn_cvt_pk_fp8_f32(a[4].x * d, a[4].y * d, 0, false);
        p = __builtin_amdgcn_cvt_pk_fp8_f32(a[5].x * d, a[5].y * d, p, true);
        o.z = (unsigned)p;
        p = __builtin_amdgcn_cvt_pk_fp8_f32(a[6].x * d, a[6].y * d, 0, false);
        p = __builtin_amdgcn_cvt_pk_fp8_f32(a[7].x * d, a[7].y * d, p, true);
        o.w = (unsigned)p;
        *(u32x4*)(out + (size_t)node * 256 + li * 16) = o;
    }
}
#undef ACC16

// ---------------------------------------------------------------- MFMA GEMM 128x128, fp8 A (decoded), bf16 B
// C[M,256] = relu(A8[M,K] @ B[K,256] + bias) [* dinv[row] if PRESCALE].
// If POOL: instead of writing C, accumulate per-graph column sums into sums[]
// (mean-pool numerator) -- h2 is never materialized.
template <int K, bool PRESCALE, bool POOL>
__global__ __launch_bounds__(256) void mgemm_kernel(const unsigned char* __restrict__ A8,
                                                    const bf16* __restrict__ Bt,
                                                    const float* __restrict__ bias,
                                                    const float* __restrict__ dinv,
                                                    unsigned char* __restrict__ C8,
                                                    const int* __restrict__ batch,
                                                    float* __restrict__ sums) {
    __shared__ short As[128][40];   // [m][k] bf16 (decoded from fp8), +8 pad
    __shared__ short Bs[128][40];   // [n][k] bf16
    const int t    = threadIdx.x;
    const int bm   = (int)(blockIdx.x >> 1) * 128;
    const int bn   = (int)(blockIdx.x & 1) * 128;
    const int lane = t & 63;
    const int wave = t >> 6;
    const int wm   = (wave >> 1) * 64, wn = (wave & 1) * 64;
    const int m16  = lane & 15, kq = lane >> 4;
    f32x4 acc[4][4] = {};

    for (int k0 = 0; k0 < K; k0 += 32) {
        // A tile: 128 rows x 32 fp8 = 4 KB, one uint4 (16 fp8) per thread, decode -> bf16 LDS
        {
            int rr = t >> 1, seg = t & 1;          // seg*16 fp8 within the 32-k tile
            uint4 va = {0u, 0u, 0u, 0u};
            int grow = bm + rr;
            if (grow < NODES) va = *(const uint4*)(A8 + (size_t)grow * K + k0 + seg * 16);
            unsigned wd[4] = {va.x, va.y, va.z, va.w};
            #pragma unroll
            for (int u = 0; u < 4; u++) {
                f32x2 lo = __builtin_amdgcn_cvt_pk_f32_fp8((int)wd[u], false);
                f32x2 hi = __builtin_amdgcn_cvt_pk_f32_fp8((int)wd[u], true);
                union { __hip_bfloat162 h[2]; u32x2 q; } pk;
                pk.h[0] = __float22bfloat162_rn(make_float2(lo.x, lo.y));
                pk.h[1] = __float22bfloat162_rn(make_float2(hi.x, hi.y));
                *(u32x2*)&As[rr][seg * 16 + u * 4] = pk.q;
            }
        }
        // B tile: 128 n-rows x 32 k bf16 = 8 KB, two uint4 per thread
        #pragma unroll
        for (int h = 0; h < 2; h++) {
            int q = t * 2 + h;
            int rr = q >> 2, seg = q & 3;
            uint4 vb = *(const uint4*)(Bt + (size_t)(bn + rr) * K + k0 + seg * 8);
            *(uint4*)&Bs[rr][seg * 8] = vb;
        }
        __syncthreads();
        bf16x8 af[4], bf_[4];
        #pragma unroll
        for (int i = 0; i < 4; i++) {
            af[i]  = *(const bf16x8*)&As[wm + i * 16 + m16][kq * 8];
            bf_[i] = *(const bf16x8*)&Bs[wn + i * 16 + m16][kq * 8];
        }
        #pragma unroll
        for (int mt = 0; mt < 4; mt++)
            #pragma unroll
            for (int nt = 0; nt < 4; nt++)
                acc[mt][nt] = __builtin_amdgcn_mfma_f32_16x16x32_bf16(af[mt], bf_[nt],
                                                                     acc[mt][nt], 0, 0, 0);
        __syncthreads();
    }

    // C/D layout: col = lane&15, row = (lane>>4)*4 + reg
    if (POOL) {
        // pooled sum accumulation; C never materialized
        bool fast = (bm + 128 <= NODES) && (batch[bm] == batch[bm + 127]);
        if (fast) {
            int g0 = batch[bm];
            #pragma unroll
            for (int nt = 0; nt < 4; nt++) {
                int colb = bn + wn + nt * 16 + m16;
                float bv = bias[colb];
                float cs = 0.f;
                #pragma unroll
                for (int mt = 0; mt < 4; mt++)
                    #pragma unroll
                    for (int r = 0; r < 4; r++)
                        cs += fmaxf(acc[mt][nt][r] + bv, 0.f);
                cs += __shfl_xor(cs, 16, 64);     // reduce over kq
                cs += __shfl_xor(cs, 32, 64);
                if (kq == 0) atomicAdd(&sums[g0 * 256 + colb], cs);
            }
        } else {
            #pragma unroll
            for (int mt = 0; mt < 4; mt++) {
                #pragma unroll
                for (int r = 0; r < 4; r++) {
                    int row = bm + wm + mt * 16 + kq * 4 + r;
                    if (row >= NODES) continue;
                    int g = batch[row];
                    #pragma unroll
                    for (int nt = 0; nt < 4; nt++) {
                        int colb = bn + wn + nt * 16 + m16;
                        float v = fmaxf(acc[mt][nt][r] + bias[colb], 0.f);
                        atomicAdd(&sums[g * 256 + colb], v);
                    }
                }
            }
        }
    } else {
        #pragma unroll
        for (int mt = 0; mt < 4; mt++) {
            #pragma unroll
            for (int r = 0; r < 4; r++) {
                int row = bm + wm + mt * 16 + kq * 4 + r;
                if (row >= NODES) continue;
                float sc = PRESCALE ? dinv[row] : 1.f;
                #pragma unroll
                for (int nt = 0; nt < 4; nt++) {
                    int colb = bn + wn + nt * 16 + m16;
                    float v = fmaxf(acc[mt][nt][r] + bias[colb], 0.f) * sc;
                    int pkd = __builtin_amdgcn_cvt_pk_fp8_f32(v, v, 0, false);
                    C8[(size_t)row * 256 + colb] = (unsigned char)(pkd & 0xff);
                }
            }
        }
    }
}

// ---------------------------------------------------------------- pooled @ Wl + bl
__global__ void final_kernel(const float* __restrict__ sums, const int* __restrict__ batch,
                             const float* __restrict__ Wl, const float* __restrict__ bl,
                             float* __restrict__ out) {
    int g = blockIdx.x;
    int l = threadIdx.x;
    int lo = 0, hi = NODES;
    while (lo < hi) { int m = (lo + hi) >> 1; if (batch[m] < g) lo = m + 1; else hi = m; }
    int lb = lo;
    lo = lb; hi = NODES;
    while (lo < hi) { int m = (lo + hi) >> 1; if (batch[m] <= g) lo = m + 1; else hi = m; }
    int cnt = lo - lb;
    float inv = 1.f / fmaxf((float)cnt, 1.f);
    float a0 = 0.f, a1 = 0.f;
    for (int k = l; k < 256; k += 64) {
        float p = sums[g * 256 + k] * inv;
        a0 += p * Wl[k * 2 + 0];
        a1 += p * Wl[k * 2 + 1];
    }
    for (int off = 32; off > 0; off >>= 1) {
        a0 += __shfl_down(a0, off, 64);
        a1 += __shfl_down(a1, off, 64);
    }
    if (l == 0) {
        out[g * 2 + 0] = a0 + bl[0];
        out[g * 2 + 1] = a1 + bl[1];
    }
}

// ---------------------------------------------------------------- launch
extern "C" void kernel_launch(void* const* d_in, const int* in_sizes, int n_in,
                              void* d_out, int out_size, void* d_ws, size_t ws_size,
                              hipStream_t stream) {
    const float* x    = (const float*)d_in[0];
    const int*   ei   = (const int*)d_in[1];
    const int*   bat  = (const int*)d_in[2];
    const float* W1   = (const float*)d_in[3];
    const float* b1   = (const float*)d_in[4];
    const float* W2   = (const float*)d_in[5];
    const float* b2   = (const float*)d_in[6];
    const float* Wl   = (const float*)d_in[7];
    const float* bl   = (const float*)d_in[8];
    float*       out  = (float*)d_out;
    const int* erow = ei;           // edge_index[0] = source
    const int* ecol = ei + EDGES;   // edge_index[1] = target

    char* p = (char*)d_ws;
    auto take = [&](size_t bytes) {
        char* r = p;
        p += (bytes + 255) & ~(size_t)255;
        return r;
    };
    float* dinv   = (float*)take((size_t)NODES * 4);
    int*   rowptr = (int*)  take((size_t)(NODES + 1) * 4);
    int*   gcnt   = (int*)  take((size_t)NBUCK * 4);
    int*   csr    = (int*)  take((size_t)ETOT * 4);
    float* sums   = (float*)take((size_t)NGRAPH * HDIM * 4);
    bf16*  W1t    = (bf16*) take((size_t)128 * 256 * 2);
    bf16*  W2t    = (bf16*) take((size_t)256 * 256 * 2);
    char*  reg1   = (char*) take((size_t)NODES * HDIM * 1);   // x8 (12.8) -> h1f8 (25.6)
    char*  reg2   = (char*) take((size_t)NODES * HDIM * 1);   // aggbuf1 (12.8) -> aggbuf2 (25.6)
    char*  reg3   = (char*) take((size_t)NODES * HDIM * 1);   // recs (16.4)
    unsigned char* x8      = (unsigned char*)reg1; // dead after agg1
    unsigned char* h1f8    = (unsigned char*)reg1; // born mgemm1, dead after agg2
    unsigned char* aggbuf1 = (unsigned char*)reg2; // born agg1, dead after mgemm1
    unsigned char* aggbuf2 = (unsigned char*)reg2; // born agg2, dead after mgemm2
    unsigned*      recs    = (unsigned*)reg3;      // dead after build

    hipMemsetAsync(sums, 0, (size_t)NGRAPH * HDIM * 4, stream);
    hipMemsetAsync(gcnt, 0, (size_t)NBUCK * 4, stream);
    wcast_kernel<<<(128 * 256 + 256 * 256 + 255) / 256, 256, 0, stream>>>(W1, W2, W1t, W2t);

    fillp1_kernel<<<(ETOT + 8191) / 8192, 1024, 0, stream>>>(erow, ecol, gcnt, recs);
    build_kernel <<<NBUCK, 256, 0, stream>>>(recs, gcnt, rowptr, dinv, csr);

    // xcast needs dinv -> after build (standalone: full-grid streaming)
    xcast_kernel<<<(NODES * 128 / 4 + 255) / 256, 256, 0, stream>>>(x, dinv, x8);

    const int AGG_BLOCKS = ((size_t)NODES * 64 + 255) / 256;  // 1 node per wave
    agg1_kernel<<<AGG_BLOCKS, 256, 0, stream>>>(x8, rowptr, csr, dinv, aggbuf1);

    const int MB = (NODES + 127) / 128;               // 782
    mgemm_kernel<128, true,  false><<<MB * 2, 256, 0, stream>>>(aggbuf1, W1t, b1, dinv, h1f8,
                                                                nullptr, nullptr);

    agg2_kernel<<<AGG_BLOCKS, 256, 0, stream>>>(h1f8, rowptr, csr, dinv, aggbuf2);

    // mgemm2 pools directly into sums (h2 never materialized)
    mgemm_kernel<256, false, true ><<<MB * 2, 256, 0, stream>>>(aggbuf2, W2t, b2, nullptr, nullptr,
                                                                bat, sums);

    final_kernel<<<NGRAPH, 64, 0, stream>>>(sums, bat, Wl, bl, out);
}

// Round 11
// 436.588 us; speedup vs baseline: 1.0719x; 1.0071x over previous
//
#include <hip/hip_runtime.h>
#include <hip/hip_bf16.h>
#include <cstddef>

#define NODES  100000
#define EDGES  3200000
#define ETOT   3300000   // EDGES + NODES self-loops
#define NGRAPH 64
#define HDIM   256
#define BSHIFT 6
#define NBUCK  1563      // ceil(NODES / 64)
#define BCAP   3136      // records/bucket: mean 2111 + ~22 sigma

typedef __hip_bfloat16 bf16;
typedef short bf16x8 __attribute__((ext_vector_type(8)));
typedef float f32x4 __attribute__((ext_vector_type(4)));
typedef float f32x2 __attribute__((ext_vector_type(2)));
typedef unsigned u32x2 __attribute__((ext_vector_type(2)));
typedef unsigned u32x4 __attribute__((ext_vector_type(4)));

// ---------------------------------------------------------------- fp32 -> fp8 of x, pre-scaled by dinv[row]
__global__ void xcast_kernel(const float* __restrict__ x, const float* __restrict__ dinv,
                             unsigned char* __restrict__ x8) {
    int i = blockIdx.x * 256 + threadIdx.x;            // 4 elements each
    if ((size_t)i * 4 >= (size_t)NODES * 128) return;
    float d = dinv[i >> 5];                            // 128 cols / 4 = 32 groups per row
    float4 v = *(const float4*)(x + (size_t)i * 4);
    int w = __builtin_amdgcn_cvt_pk_fp8_f32(v.x * d, v.y * d, 0, false);
    w     = __builtin_amdgcn_cvt_pk_fp8_f32(v.z * d, v.w * d, w, true);
    *(unsigned*)(x8 + (size_t)i * 4) = (unsigned)w;
}

// ---------------------------------------------------------------- W1/W2 -> transposed bf16
__global__ void wcast_kernel(const float* __restrict__ W1, const float* __restrict__ W2,
                             bf16* __restrict__ W1t, bf16* __restrict__ W2t) {
    int i = blockIdx.x * 256 + threadIdx.x;
    if (i < 128 * 256) {
        int n = i / 128, k = i - n * 128;
        W1t[i] = __float2bfloat16(W1[(size_t)k * 256 + n]);
    } else if (i < 128 * 256 + 256 * 256) {
        int q = i - 128 * 256;
        int n = q / 256, k = q - n * 256;
        W2t[q] = __float2bfloat16(W2[(size_t)k * 256 + n]);
    }
}

// ---------------------------------------------------------------- fill phase 1: 4-byte bucket records
// rec = (src << 6) | local_dst. 4-copy LDS histogram quarters rank-atomic collisions.
__global__ __launch_bounds__(1024) void fillp1_kernel(const int* __restrict__ row,
                                                      const int* __restrict__ col,
                                                      int* __restrict__ gcnt,
                                                      unsigned* __restrict__ recs) {
    __shared__ int hist[4][NBUCK];
    __shared__ int coff[4][NBUCK];
    __shared__ int base[NBUCK];
    int t  = threadIdx.x;
    int cp = t & 3;
    for (int i = t; i < 4 * NBUCK; i += 1024) ((int*)hist)[i] = 0;
    __syncthreads();
    int e0 = blockIdx.x * 8192;
    int r[8], c[8], rk[8];
    #pragma unroll
    for (int i = 0; i < 8; i++) {
        int e = e0 + i * 1024 + t;
        r[i] = -1;
        if (e < ETOT) {
            if (e < EDGES) { r[i] = row[e]; c[i] = col[e]; }
            else           { r[i] = e - EDGES; c[i] = r[i]; }
            rk[i] = atomicAdd(&hist[cp][c[i] >> BSHIFT], 1);
        }
    }
    __syncthreads();
    for (int b = t; b < NBUCK; b += 1024) {
        int h0 = hist[0][b], h1 = hist[1][b], h2 = hist[2][b], h3 = hist[3][b];
        coff[0][b] = 0; coff[1][b] = h0; coff[2][b] = h0 + h1; coff[3][b] = h0 + h1 + h2;
        int tot = h0 + h1 + h2 + h3;
        base[b] = (tot > 0) ? atomicAdd(&gcnt[b], tot) : 0;
    }
    __syncthreads();
    #pragma unroll
    for (int i = 0; i < 8; i++) {
        if (r[i] >= 0) {
            int b = c[i] >> BSHIFT;
            recs[(size_t)b * BCAP + base[b] + coff[cp][b] + rk[i]] =
                ((unsigned)r[i] << BSHIFT) | (unsigned)(c[i] & 63);
        }
    }
}

// ---------------------------------------------------------------- per-bucket counting sort (64 nodes/bucket)
// 1563 blocks (6/CU); per-block record count ~2.1K -> short latency chains.
__global__ __launch_bounds__(256) void build_kernel(const unsigned* __restrict__ recs,
                                                    const int* __restrict__ gcnt,
                                                    int* __restrict__ rowptr,
                                                    float* __restrict__ dinv,
                                                    int* __restrict__ csr) {
    __shared__ int hist[64];
    __shared__ int cur[64];
    __shared__ int part[256];
    __shared__ int sbase;
    const int b = blockIdx.x, t = threadIdx.x;
    const int cnt = gcnt[b];
    const int n0 = b << BSHIFT;
    // block-internal exclusive prefix: base = sum gcnt[0..b)  (<= 7 strided loads)
    int pv = 0;
    for (int idx = t; idx < b; idx += 256) pv += gcnt[idx];
    part[t] = pv;
    __syncthreads();
    for (int off = 128; off >= 1; off >>= 1) {
        if (t < off) part[t] += part[t + off];
        __syncthreads();
    }
    if (t == 0) sbase = part[0];
    __syncthreads();
    const int base = sbase;
    if (t < 64) hist[t] = 0;
    __syncthreads();
    const unsigned* rb = recs + (size_t)b * BCAP;
    for (int i = t; i < cnt; i += 256) atomicAdd(&hist[rb[i] & 63u], 1);
    __syncthreads();
    int h0 = (t < 64) ? hist[t] : 0;
    part[t] = h0;
    __syncthreads();
    for (int off = 1; off < 64; off <<= 1) {
        int v = (t >= off && t < 64) ? part[t - off] : 0;
        __syncthreads();
        if (t < 64) part[t] += v;
        __syncthreads();
    }
    if (t < 64) {
        int ex = (t == 0) ? 0 : part[t - 1];   // exclusive over nodes
        cur[t] = ex;
        int v0 = n0 + t;
        if (v0 < NODES) { rowptr[v0] = base + ex; dinv[v0] = rsqrtf((float)h0); }
    }
    if (b == 0 && t == 0) rowptr[NODES] = ETOT;
    __syncthreads();
    for (int i = t; i < cnt; i += 256) {
        unsigned r = rb[i];
        int pos = atomicAdd(&cur[r & 63u], 1);
        csr[base + pos] = (int)(r >> BSHIFT);
    }
}

#define ACC16(q) do {                                                      \
        a[0] += __builtin_amdgcn_cvt_pk_f32_fp8((int)(q).x, false);        \
        a[1] += __builtin_amdgcn_cvt_pk_f32_fp8((int)(q).x, true);         \
        a[2] += __builtin_amdgcn_cvt_pk_f32_fp8((int)(q).y, false);        \
        a[3] += __builtin_amdgcn_cvt_pk_f32_fp8((int)(q).y, true);         \
        a[4] += __builtin_amdgcn_cvt_pk_f32_fp8((int)(q).z, false);        \
        a[5] += __builtin_amdgcn_cvt_pk_f32_fp8((int)(q).z, true);         \
        a[6] += __builtin_amdgcn_cvt_pk_f32_fp8((int)(q).w, false);        \
        a[7] += __builtin_amdgcn_cvt_pk_f32_fp8((int)(q).w, true);         \
    } while (0)

// ---------------------------------------------------------------- pull aggregation, H=128, fp8 in/out
// One node per wave; 8 lane-groups of 8 lanes; 16B/lane loads (8 lanes x 16B = 128B/row).
__global__ void agg1_kernel(const unsigned char* __restrict__ x8, const int* __restrict__ rowptr,
                            const int* __restrict__ csr, const float* __restrict__ dinv,
                            unsigned char* __restrict__ out) {
    int node = (blockIdx.x * blockDim.x + threadIdx.x) >> 6;
    if (node >= NODES) return;
    int lane = threadIdx.x & 63;
    int sub  = lane >> 3, li = lane & 7;
    int beg = rowptr[node], end = rowptr[node + 1];
    float d = dinv[node];
    f32x2 a[8] = {};
    int j = beg;
    int nb = (end - beg) >> 5;
    if (nb > 0) {
        int i0 = csr[j + sub],      i1 = csr[j + 8 + sub];
        int i2 = csr[j + 16 + sub], i3 = csr[j + 24 + sub];
        for (int b = 1; b <= nb; ++b) {
            u32x4 q0 = *(const u32x4*)(x8 + (size_t)i0 * 128 + li * 16);
            u32x4 q1 = *(const u32x4*)(x8 + (size_t)i1 * 128 + li * 16);
            u32x4 q2 = *(const u32x4*)(x8 + (size_t)i2 * 128 + li * 16);
            u32x4 q3 = *(const u32x4*)(x8 + (size_t)i3 * 128 + li * 16);
            j += 32;
            if (b < nb) {
                i0 = csr[j + sub];      i1 = csr[j + 8 + sub];
                i2 = csr[j + 16 + sub]; i3 = csr[j + 24 + sub];
            }
            ACC16(q0); ACC16(q1); ACC16(q2); ACC16(q3);
        }
    }
    for (; j + 7 < end; j += 8) {
        int s = csr[j + sub];
        u32x4 q = *(const u32x4*)(x8 + (size_t)s * 128 + li * 16);
        ACC16(q);
    }
    if (j + sub < end) {
        int s = csr[j + sub];
        u32x4 q = *(const u32x4*)(x8 + (size_t)s * 128 + li * 16);
        ACC16(q);
    }
    // combine the 8 lane-groups: xor 8, 16, 32
    #pragma unroll
    for (int i = 0; i < 8; i++) {
        a[i].x += __shfl_xor(a[i].x, 8, 64);
        a[i].y += __shfl_xor(a[i].y, 8, 64);
        a[i].x += __shfl_xor(a[i].x, 16, 64);
        a[i].y += __shfl_xor(a[i].y, 16, 64);
        a[i].x += __shfl_xor(a[i].x, 32, 64);
        a[i].y += __shfl_xor(a[i].y, 32, 64);
    }
    if (sub == 0) {
        u32x4 o;
        int p;
        p = __builtin_amdgcn_cvt_pk_fp8_f32(a[0].x * d, a[0].y * d, 0, false);
        p = __builtin_amdgcn_cvt_pk_fp8_f32(a[1].x * d, a[1].y * d, p, true);
        o.x = (unsigned)p;
        p = __builtin_amdgcn_cvt_pk_fp8_f32(a[2].x * d, a[2].y * d, 0, false);
        p = __builtin_amdgcn_cvt_pk_fp8_f32(a[3].x * d, a[3].y * d, p, true);
        o.y = (unsigned)p;
        p = __builtin_amdgcn_cvt_pk_fp8_f32(a[4].x * d, a[4].y * d, 0, false);
        p = __builtin_amdgcn_cvt_pk_fp8_f32(a[5].x * d, a[5].y * d, p, true);
        o.z = (unsigned)p;
        p = __builtin_amdgcn_cvt_pk_fp8_f32(a[6].x * d, a[6].y * d, 0, false);
        p = __builtin_amdgcn_cvt_pk_fp8_f32(a[7].x * d, a[7].y * d, p, true);
        o.w = (unsigned)p;
        *(u32x4*)(out + (size_t)node * 128 + li * 16) = o;
    }
}

// ---------------------------------------------------------------- pull aggregation, H=256, fp8 in/out
// One node per wave; 4 lane-groups of 16 lanes; 16B/lane loads (16 lanes x 16B = 256B/row).
__global__ void agg2_kernel(const unsigned char* __restrict__ h8, const int* __restrict__ rowptr,
                            const int* __restrict__ csr, const float* __restrict__ dinv,
                            unsigned char* __restrict__ out) {
    int node = (blockIdx.x * blockDim.x + threadIdx.x) >> 6;
    if (node >= NODES) return;
    int lane = threadIdx.x & 63;
    int sub  = lane >> 4, li = lane & 15;
    int beg = rowptr[node], end = rowptr[node + 1];
    float d = dinv[node];
    f32x2 a[8] = {};
    int j = beg;
    int nb = (end - beg) >> 4;
    if (nb > 0) {
        int i0 = csr[j + sub],     i1 = csr[j + 4 + sub];
        int i2 = csr[j + 8 + sub], i3 = csr[j + 12 + sub];
        for (int b = 1; b <= nb; ++b) {
            u32x4 q0 = *(const u32x4*)(h8 + (size_t)i0 * 256 + li * 16);
            u32x4 q1 = *(const u32x4*)(h8 + (size_t)i1 * 256 + li * 16);
            u32x4 q2 = *(const u32x4*)(h8 + (size_t)i2 * 256 + li * 16);
            u32x4 q3 = *(const u32x4*)(h8 + (size_t)i3 * 256 + li * 16);
            j += 16;
            if (b < nb) {
                i0 = csr[j + sub];     i1 = csr[j + 4 + sub];
                i2 = csr[j + 8 + sub]; i3 = csr[j + 12 + sub];
            }
            ACC16(q0); ACC16(q1); ACC16(q2); ACC16(q3);
        }
    }
    for (; j + 3 < end; j += 4) {
        int s = csr[j + sub];
        u32x4 q = *(const u32x4*)(h8 + (size_t)s * 256 + li * 16);
        ACC16(q);
    }
    if (j + sub < end) {
        int s = csr[j + sub];
        u32x4 q = *(const u32x4*)(h8 + (size_t)s * 256 + li * 16);
        ACC16(q);
    }
    // combine the 4 lane-groups: xor 16, 32
    #pragma unroll
    for (int i = 0; i < 8; i++) {
        a[i].x += __shfl_xor(a[i].x, 16, 64);
        a[i].y += __shfl_xor(a[i].y, 16, 64);
        a[i].x += __shfl_xor(a[i].x, 32, 64);
        a[i].y += __shfl_xor(a[i].y, 32, 64);
    }
    if (sub == 0) {
        u32x4 o;
        int p;
        p = __builtin_amdgcn_cvt_pk_fp8_f32(a[0].x * d, a[0].y * d, 0, false);
        p = __builtin_amdgcn_cvt_pk_fp8_f32(a[1].x * d, a[1].y * d, p, true);
        o.x = (unsigned)p;
        p = __builtin_amdgcn_cvt_pk_fp8_f32(a[2].x * d, a[2].y * d, 0, false);
        p = __builtin_amdgcn_cvt_pk_fp8_f32(a[3].x * d, a[3].y * d, p, true);
        o.y = (unsigned)p;
        p = __builtin_amdgcn_cvt_pk_fp8_f32(a[4].x * d, a[4].y * d, 0, false);
        p = __builtin_amdgcn_cvt_pk_fp8_f32(a[5].x * d, a[5].y * d, p, true);
        o.z = (unsigned)p;
        p = __builtin_amdgcn_cvt_pk_fp8_f32(a[6].x * d, a[6].y * d, 0, false);
        p = __builtin_amdgcn_cvt_pk_fp8_f32(a[7].x * d, a[7].y * d, p, true);
        o.w = (unsigned)p;
        *(u32x4*)(out + (size_t)node * 256 + li * 16) = o;
    }
}
#undef ACC16

// ---------------------------------------------------------------- MFMA GEMM 128x256, fp8 A (decoded), bf16 B
// 512 threads, 8 waves (2 wm x 4 wn of 64x64). A read ONCE per block (no bn split).
// C[M,256] = relu(A8[M,K] @ B[K,256] + bias) [* dinv[row] if PRESCALE].
// If POOL: accumulate per-graph column sums into sums[] instead of writing C.
template <int K, bool PRESCALE, bool POOL>
__global__ __launch_bounds__(512) void mgemm_kernel(const unsigned char* __restrict__ A8,
                                                    const bf16* __restrict__ Bt,
                                                    const float* __restrict__ bias,
                                                    const float* __restrict__ dinv,
                                                    unsigned char* __restrict__ C8,
                                                    const int* __restrict__ batch,
                                                    float* __restrict__ sums) {
    __shared__ short As[128][40];   // [m][k] bf16 (decoded from fp8), +8 pad (80B = 5x16B rows)
    __shared__ short Bs[256][40];   // [n][k] bf16
    const int t    = threadIdx.x;
    const int bm   = blockIdx.x * 128;
    const int lane = t & 63;
    const int wave = t >> 6;                     // 0..7
    const int wm   = (wave >> 2) * 64;           // 0,64
    const int wn   = (wave & 3) * 64;            // 0,64,128,192
    const int m16  = lane & 15, kq = lane >> 4;
    f32x4 acc[4][4] = {};

    for (int k0 = 0; k0 < K; k0 += 32) {
        // A tile: 128 rows x 32 fp8 = 4 KB, one u32x2 (8 fp8) per thread, decode -> bf16 LDS
        {
            int rr = t >> 2, seg = t & 3;        // seg*8 fp8 within the 32-k tile
            u32x2 va = {0u, 0u};
            int grow = bm + rr;
            if (grow < NODES) va = *(const u32x2*)(A8 + (size_t)grow * K + k0 + seg * 8);
            f32x2 l0 = __builtin_amdgcn_cvt_pk_f32_fp8((int)va.x, false);
            f32x2 h0 = __builtin_amdgcn_cvt_pk_f32_fp8((int)va.x, true);
            f32x2 l1 = __builtin_amdgcn_cvt_pk_f32_fp8((int)va.y, false);
            f32x2 h1 = __builtin_amdgcn_cvt_pk_f32_fp8((int)va.y, true);
            union { __hip_bfloat162 h[4]; u32x4 q; } pk;
            pk.h[0] = __float22bfloat162_rn(make_float2(l0.x, l0.y));
            pk.h[1] = __float22bfloat162_rn(make_float2(h0.x, h0.y));
            pk.h[2] = __float22bfloat162_rn(make_float2(l1.x, l1.y));
            pk.h[3] = __float22bfloat162_rn(make_float2(h1.x, h1.y));
            *(u32x4*)&As[rr][seg * 8] = pk.q;
        }
        // B tile: 256 n-rows x 32 k bf16 = 16 KB, two uint4 per thread
        #pragma unroll
        for (int h = 0; h < 2; h++) {
            int q = t * 2 + h;                   // 0..1023
            int rr = q >> 2, seg = q & 3;
            uint4 vb = *(const uint4*)(Bt + (size_t)rr * K + k0 + seg * 8);
            *(uint4*)&Bs[rr][seg * 8] = vb;
        }
        __syncthreads();
        bf16x8 af[4], bf_[4];
        #pragma unroll
        for (int i = 0; i < 4; i++) {
            af[i]  = *(const bf16x8*)&As[wm + i * 16 + m16][kq * 8];
            bf_[i] = *(const bf16x8*)&Bs[wn + i * 16 + m16][kq * 8];
        }
        #pragma unroll
        for (int mt = 0; mt < 4; mt++)
            #pragma unroll
            for (int nt = 0; nt < 4; nt++)
                acc[mt][nt] = __builtin_amdgcn_mfma_f32_16x16x32_bf16(af[mt], bf_[nt],
                                                                     acc[mt][nt], 0, 0, 0);
        __syncthreads();
    }

    // C/D layout: col = lane&15, row = (lane>>4)*4 + reg
    if (POOL) {
        bool fast = (bm + 128 <= NODES) && (batch[bm] == batch[bm + 127]);
        if (fast) {
            int g0 = batch[bm];
            #pragma unroll
            for (int nt = 0; nt < 4; nt++) {
                int colb = wn + nt * 16 + m16;
                float bv = bias[colb];
                float cs = 0.f;
                #pragma unroll
                for (int mt = 0; mt < 4; mt++)
                    #pragma unroll
                    for (int r = 0; r < 4; r++)
                        cs += fmaxf(acc[mt][nt][r] + bv, 0.f);
                cs += __shfl_xor(cs, 16, 64);     // reduce over kq
                cs += __shfl_xor(cs, 32, 64);
                if (kq == 0) atomicAdd(&sums[g0 * 256 + colb], cs);
            }
        } else {
            #pragma unroll
            for (int mt = 0; mt < 4; mt++) {
                #pragma unroll
                for (int r = 0; r < 4; r++) {
                    int row = bm + wm + mt * 16 + kq * 4 + r;
                    if (row >= NODES) continue;
                    int g = batch[row];
                    #pragma unroll
                    for (int nt = 0; nt < 4; nt++) {
                        int colb = wn + nt * 16 + m16;
                        float v = fmaxf(acc[mt][nt][r] + bias[colb], 0.f);
                        atomicAdd(&sums[g * 256 + colb], v);
                    }
                }
            }
        }
    } else {
        #pragma unroll
        for (int mt = 0; mt < 4; mt++) {
            #pragma unroll
            for (int r = 0; r < 4; r++) {
                int row = bm + wm + mt * 16 + kq * 4 + r;
                if (row >= NODES) continue;
                float sc = PRESCALE ? dinv[row] : 1.f;
                #pragma unroll
                for (int nt = 0; nt < 4; nt++) {
                    int colb = wn + nt * 16 + m16;
                    float v = fmaxf(acc[mt][nt][r] + bias[colb], 0.f) * sc;
                    int pkd = __builtin_amdgcn_cvt_pk_fp8_f32(v, v, 0, false);
                    C8[(size_t)row * 256 + colb] = (unsigned char)(pkd & 0xff);
                }
            }
        }
    }
}

// ---------------------------------------------------------------- pooled @ Wl + bl
__global__ void final_kernel(const float* __restrict__ sums, const int* __restrict__ batch,
                             const float* __restrict__ Wl, const float* __restrict__ bl,
                             float* __restrict__ out) {
    int g = blockIdx.x;
    int l = threadIdx.x;
    int lo = 0, hi = NODES;
    while (lo < hi) { int m = (lo + hi) >> 1; if (batch[m] < g) lo = m + 1; else hi = m; }
    int lb = lo;
    lo = lb; hi = NODES;
    while (lo < hi) { int m = (lo + hi) >> 1; if (batch[m] <= g) lo = m + 1; else hi = m; }
    int cnt = lo - lb;
    float inv = 1.f / fmaxf((float)cnt, 1.f);
    float a0 = 0.f, a1 = 0.f;
    for (int k = l; k < 256; k += 64) {
        float p = sums[g * 256 + k] * inv;
        a0 += p * Wl[k * 2 + 0];
        a1 += p * Wl[k * 2 + 1];
    }
    for (int off = 32; off > 0; off >>= 1) {
        a0 += __shfl_down(a0, off, 64);
        a1 += __shfl_down(a1, off, 64);
    }
    if (l == 0) {
        out[g * 2 + 0] = a0 + bl[0];
        out[g * 2 + 1] = a1 + bl[1];
    }
}

// ---------------------------------------------------------------- launch
extern "C" void kernel_launch(void* const* d_in, const int* in_sizes, int n_in,
                              void* d_out, int out_size, void* d_ws, size_t ws_size,
                              hipStream_t stream) {
    const float* x    = (const float*)d_in[0];
    const int*   ei   = (const int*)d_in[1];
    const int*   bat  = (const int*)d_in[2];
    const float* W1   = (const float*)d_in[3];
    const float* b1   = (const float*)d_in[4];
    const float* W2   = (const float*)d_in[5];
    const float* b2   = (const float*)d_in[6];
    const float* Wl   = (const float*)d_in[7];
    const float* bl   = (const float*)d_in[8];
    float*       out  = (float*)d_out;
    const int* erow = ei;           // edge_index[0] = source
    const int* ecol = ei + EDGES;   // edge_index[1] = target

    char* p = (char*)d_ws;
    auto take = [&](size_t bytes) {
        char* r = p;
        p += (bytes + 255) & ~(size_t)255;
        return r;
    };
    float* dinv   = (float*)take((size_t)NODES * 4);
    int*   rowptr = (int*)  take((size_t)(NODES + 1) * 4);
    int*   gcnt   = (int*)  take((size_t)NBUCK * 4);
    int*   csr    = (int*)  take((size_t)ETOT * 4);
    float* sums   = (float*)take((size_t)NGRAPH * HDIM * 4);
    bf16*  W1t    = (bf16*) take((size_t)128 * 256 * 2);
    bf16*  W2t    = (bf16*) take((size_t)256 * 256 * 2);
    char*  reg1   = (char*) take((size_t)NODES * HDIM * 1);   // x8 (12.8) -> h1f8 (25.6)
    char*  reg2   = (char*) take((size_t)NODES * HDIM * 1);   // aggbuf1 (12.8) -> aggbuf2 (25.6)
    char*  reg3   = (char*) take((size_t)NODES * HDIM * 1);   // recs (19.6)
    unsigned char* x8      = (unsigned char*)reg1; // dead after agg1
    unsigned char* h1f8    = (unsigned char*)reg1; // born mgemm1, dead after agg2
    unsigned char* aggbuf1 = (unsigned char*)reg2; // born agg1, dead after mgemm1
    unsigned char* aggbuf2 = (unsigned char*)reg2; // born agg2, dead after mgemm2
    unsigned*      recs    = (unsigned*)reg3;      // dead after build

    hipMemsetAsync(sums, 0, (size_t)NGRAPH * HDIM * 4, stream);
    hipMemsetAsync(gcnt, 0, (size_t)NBUCK * 4, stream);
    wcast_kernel<<<(128 * 256 + 256 * 256 + 255) / 256, 256, 0, stream>>>(W1, W2, W1t, W2t);

    fillp1_kernel<<<(ETOT + 8191) / 8192, 1024, 0, stream>>>(erow, ecol, gcnt, recs);
    build_kernel <<<NBUCK, 256, 0, stream>>>(recs, gcnt, rowptr, dinv, csr);

    // xcast needs dinv -> after build (standalone: full-grid streaming)
    xcast_kernel<<<(NODES * 128 / 4 + 255) / 256, 256, 0, stream>>>(x, dinv, x8);

    const int AGG_BLOCKS = ((size_t)NODES * 64 + 255) / 256;  // 1 node per wave
    agg1_kernel<<<AGG_BLOCKS, 256, 0, stream>>>(x8, rowptr, csr, dinv, aggbuf1);

    const int MB = (NODES + 127) / 128;               // 782 (one block per 128 rows, full 256 cols)
    mgemm_kernel<128, true,  false><<<MB, 512, 0, stream>>>(aggbuf1, W1t, b1, dinv, h1f8,
                                                            nullptr, nullptr);

    agg2_kernel<<<AGG_BLOCKS, 256, 0, stream>>>(h1f8, rowptr, csr, dinv, aggbuf2);

    // mgemm2 pools directly into sums (h2 never materialized)
    mgemm_kernel<256, false, true ><<<MB, 512, 0, stream>>>(aggbuf2, W2t, b2, nullptr, nullptr,
                                                            bat, sums);

    final_kernel<<<NGRAPH, 64, 0, stream>>>(sums, bat, Wl, bl, out);
}

// Round 12
// 436.227 us; speedup vs baseline: 1.0728x; 1.0008x over previous
//
#include <hip/hip_runtime.h>
#include <hip/hip_bf16.h>
#include <cstddef>

#define NODES  100000
#define EDGES  3200000
#define ETOT   3300000   // EDGES + NODES self-loops
#define NGRAPH 64
#define HDIM   256
#define BSHIFT 6
#define NBUCK  1563      // ceil(NODES / 64)
#define BCAP   3136      // records/bucket: mean 2111 + ~22 sigma

typedef __hip_bfloat16 bf16;
typedef short bf16x8 __attribute__((ext_vector_type(8)));
typedef float f32x4 __attribute__((ext_vector_type(4)));
typedef float f32x2 __attribute__((ext_vector_type(2)));
typedef unsigned u32x2 __attribute__((ext_vector_type(2)));
typedef unsigned u32x4 __attribute__((ext_vector_type(4)));

// ---------------------------------------------------------------- fp32 -> fp8 of x, pre-scaled by dinv[row]
__global__ void xcast_kernel(const float* __restrict__ x, const float* __restrict__ dinv,
                             unsigned char* __restrict__ x8) {
    int i = blockIdx.x * 256 + threadIdx.x;            // 4 elements each
    if ((size_t)i * 4 >= (size_t)NODES * 128) return;
    float d = dinv[i >> 5];                            // 128 cols / 4 = 32 groups per row
    float4 v = *(const float4*)(x + (size_t)i * 4);
    int w = __builtin_amdgcn_cvt_pk_fp8_f32(v.x * d, v.y * d, 0, false);
    w     = __builtin_amdgcn_cvt_pk_fp8_f32(v.z * d, v.w * d, w, true);
    *(unsigned*)(x8 + (size_t)i * 4) = (unsigned)w;
}

// ---------------------------------------------------------------- W1/W2 -> transposed bf16
__global__ void wcast_kernel(const float* __restrict__ W1, const float* __restrict__ W2,
                             bf16* __restrict__ W1t, bf16* __restrict__ W2t) {
    int i = blockIdx.x * 256 + threadIdx.x;
    if (i < 128 * 256) {
        int n = i / 128, k = i - n * 128;
        W1t[i] = __float2bfloat16(W1[(size_t)k * 256 + n]);
    } else if (i < 128 * 256 + 256 * 256) {
        int q = i - 128 * 256;
        int n = q / 256, k = q - n * 256;
        W2t[q] = __float2bfloat16(W2[(size_t)k * 256 + n]);
    }
}

// ---------------------------------------------------------------- fill phase 1: 4-byte bucket records
// rec = (src << 6) | local_dst. 4-copy LDS histogram quarters rank-atomic collisions.
__global__ __launch_bounds__(1024) void fillp1_kernel(const int* __restrict__ row,
                                                      const int* __restrict__ col,
                                                      int* __restrict__ gcnt,
                                                      unsigned* __restrict__ recs) {
    __shared__ int hist[4][NBUCK];
    __shared__ int coff[4][NBUCK];
    __shared__ int base[NBUCK];
    int t  = threadIdx.x;
    int cp = t & 3;
    for (int i = t; i < 4 * NBUCK; i += 1024) ((int*)hist)[i] = 0;
    __syncthreads();
    int e0 = blockIdx.x * 8192;
    int r[8], c[8], rk[8];
    #pragma unroll
    for (int i = 0; i < 8; i++) {
        int e = e0 + i * 1024 + t;
        r[i] = -1;
        if (e < ETOT) {
            if (e < EDGES) { r[i] = row[e]; c[i] = col[e]; }
            else           { r[i] = e - EDGES; c[i] = r[i]; }
            rk[i] = atomicAdd(&hist[cp][c[i] >> BSHIFT], 1);
        }
    }
    __syncthreads();
    for (int b = t; b < NBUCK; b += 1024) {
        int h0 = hist[0][b], h1 = hist[1][b], h2 = hist[2][b], h3 = hist[3][b];
        coff[0][b] = 0; coff[1][b] = h0; coff[2][b] = h0 + h1; coff[3][b] = h0 + h1 + h2;
        int tot = h0 + h1 + h2 + h3;
        base[b] = (tot > 0) ? atomicAdd(&gcnt[b], tot) : 0;
    }
    __syncthreads();
    #pragma unroll
    for (int i = 0; i < 8; i++) {
        if (r[i] >= 0) {
            int b = c[i] >> BSHIFT;
            recs[(size_t)b * BCAP + base[b] + coff[cp][b] + rk[i]] =
                ((unsigned)r[i] << BSHIFT) | (unsigned)(c[i] & 63);
        }
    }
}

// ---------------------------------------------------------------- per-bucket counting sort (64 nodes/bucket)
__global__ __launch_bounds__(256) void build_kernel(const unsigned* __restrict__ recs,
                                                    const int* __restrict__ gcnt,
                                                    int* __restrict__ rowptr,
                                                    float* __restrict__ dinv,
                                                    int* __restrict__ csr) {
    __shared__ int hist[64];
    __shared__ int cur[64];
    __shared__ int part[256];
    __shared__ int sbase;
    const int b = blockIdx.x, t = threadIdx.x;
    const int cnt = gcnt[b];
    const int n0 = b << BSHIFT;
    int pv = 0;
    for (int idx = t; idx < b; idx += 256) pv += gcnt[idx];
    part[t] = pv;
    __syncthreads();
    for (int off = 128; off >= 1; off >>= 1) {
        if (t < off) part[t] += part[t + off];
        __syncthreads();
    }
    if (t == 0) sbase = part[0];
    __syncthreads();
    const int base = sbase;
    if (t < 64) hist[t] = 0;
    __syncthreads();
    const unsigned* rb = recs + (size_t)b * BCAP;
    for (int i = t; i < cnt; i += 256) atomicAdd(&hist[rb[i] & 63u], 1);
    __syncthreads();
    int h0 = (t < 64) ? hist[t] : 0;
    part[t] = h0;
    __syncthreads();
    for (int off = 1; off < 64; off <<= 1) {
        int v = (t >= off && t < 64) ? part[t - off] : 0;
        __syncthreads();
        if (t < 64) part[t] += v;
        __syncthreads();
    }
    if (t < 64) {
        int ex = (t == 0) ? 0 : part[t - 1];   // exclusive over nodes
        cur[t] = ex;
        int v0 = n0 + t;
        if (v0 < NODES) { rowptr[v0] = base + ex; dinv[v0] = rsqrtf((float)h0); }
    }
    if (b == 0 && t == 0) rowptr[NODES] = ETOT;
    __syncthreads();
    for (int i = t; i < cnt; i += 256) {
        unsigned r = rb[i];
        int pos = atomicAdd(&cur[r & 63u], 1);
        csr[base + pos] = (int)(r >> BSHIFT);
    }
}

#define ACC16(q) do {                                                      \
        a[0] += __builtin_amdgcn_cvt_pk_f32_fp8((int)(q).x, false);        \
        a[1] += __builtin_amdgcn_cvt_pk_f32_fp8((int)(q).x, true);         \
        a[2] += __builtin_amdgcn_cvt_pk_f32_fp8((int)(q).y, false);        \
        a[3] += __builtin_amdgcn_cvt_pk_f32_fp8((int)(q).y, true);         \
        a[4] += __builtin_amdgcn_cvt_pk_f32_fp8((int)(q).z, false);        \
        a[5] += __builtin_amdgcn_cvt_pk_f32_fp8((int)(q).z, true);         \
        a[6] += __builtin_amdgcn_cvt_pk_f32_fp8((int)(q).w, false);        \
        a[7] += __builtin_amdgcn_cvt_pk_f32_fp8((int)(q).w, true);         \
    } while (0)

// ---------------------------------------------------------------- pull aggregation, H=128, fp8 in/out
// One node per wave; 8 lane-groups of 8 lanes; 16B/lane loads (8 lanes x 16B = 128B/row).
__global__ void agg1_kernel(const unsigned char* __restrict__ x8, const int* __restrict__ rowptr,
                            const int* __restrict__ csr, const float* __restrict__ dinv,
                            unsigned char* __restrict__ out) {
    int node = (blockIdx.x * blockDim.x + threadIdx.x) >> 6;
    if (node >= NODES) return;
    int lane = threadIdx.x & 63;
    int sub  = lane >> 3, li = lane & 7;
    int beg = rowptr[node], end = rowptr[node + 1];
    float d = dinv[node];
    f32x2 a[8] = {};
    int j = beg;
    int nb = (end - beg) >> 5;
    if (nb > 0) {
        int i0 = csr[j + sub],      i1 = csr[j + 8 + sub];
        int i2 = csr[j + 16 + sub], i3 = csr[j + 24 + sub];
        for (int b = 1; b <= nb; ++b) {
            u32x4 q0 = *(const u32x4*)(x8 + (size_t)i0 * 128 + li * 16);
            u32x4 q1 = *(const u32x4*)(x8 + (size_t)i1 * 128 + li * 16);
            u32x4 q2 = *(const u32x4*)(x8 + (size_t)i2 * 128 + li * 16);
            u32x4 q3 = *(const u32x4*)(x8 + (size_t)i3 * 128 + li * 16);
            j += 32;
            if (b < nb) {
                i0 = csr[j + sub];      i1 = csr[j + 8 + sub];
                i2 = csr[j + 16 + sub]; i3 = csr[j + 24 + sub];
            }
            ACC16(q0); ACC16(q1); ACC16(q2); ACC16(q3);
        }
    }
    for (; j + 7 < end; j += 8) {
        int s = csr[j + sub];
        u32x4 q = *(const u32x4*)(x8 + (size_t)s * 128 + li * 16);
        ACC16(q);
    }
    if (j + sub < end) {
        int s = csr[j + sub];
        u32x4 q = *(const u32x4*)(x8 + (size_t)s * 128 + li * 16);
        ACC16(q);
    }
    // combine the 8 lane-groups: xor 8, 16, 32
    #pragma unroll
    for (int i = 0; i < 8; i++) {
        a[i].x += __shfl_xor(a[i].x, 8, 64);
        a[i].y += __shfl_xor(a[i].y, 8, 64);
        a[i].x += __shfl_xor(a[i].x, 16, 64);
        a[i].y += __shfl_xor(a[i].y, 16, 64);
        a[i].x += __shfl_xor(a[i].x, 32, 64);
        a[i].y += __shfl_xor(a[i].y, 32, 64);
    }
    if (sub == 0) {
        u32x4 o;
        int p;
        p = __builtin_amdgcn_cvt_pk_fp8_f32(a[0].x * d, a[0].y * d, 0, false);
        p = __builtin_amdgcn_cvt_pk_fp8_f32(a[1].x * d, a[1].y * d, p, true);
        o.x = (unsigned)p;
        p = __builtin_amdgcn_cvt_pk_fp8_f32(a[2].x * d, a[2].y * d, 0, false);
        p = __builtin_amdgcn_cvt_pk_fp8_f32(a[3].x * d, a[3].y * d, p, true);
        o.y = (unsigned)p;
        p = __builtin_amdgcn_cvt_pk_fp8_f32(a[4].x * d, a[4].y * d, 0, false);
        p = __builtin_amdgcn_cvt_pk_fp8_f32(a[5].x * d, a[5].y * d, p, true);
        o.z = (unsigned)p;
        p = __builtin_amdgcn_cvt_pk_fp8_f32(a[6].x * d, a[6].y * d, 0, false);
        p = __builtin_amdgcn_cvt_pk_fp8_f32(a[7].x * d, a[7].y * d, p, true);
        o.w = (unsigned)p;
        *(u32x4*)(out + (size_t)node * 128 + li * 16) = o;
    }
}

// ---------------------------------------------------------------- pull aggregation, H=256, fp8 in/out
// One node per wave; 4 lane-groups of 16 lanes; 16B/lane loads (16 lanes x 16B = 256B/row).
__global__ void agg2_kernel(const unsigned char* __restrict__ h8, const int* __restrict__ rowptr,
                            const int* __restrict__ csr, const float* __restrict__ dinv,
                            unsigned char* __restrict__ out) {
    int node = (blockIdx.x * blockDim.x + threadIdx.x) >> 6;
    if (node >= NODES) return;
    int lane = threadIdx.x & 63;
    int sub  = lane >> 4, li = lane & 15;
    int beg = rowptr[node], end = rowptr[node + 1];
    float d = dinv[node];
    f32x2 a[8] = {};
    int j = beg;
    int nb = (end - beg) >> 4;
    if (nb > 0) {
        int i0 = csr[j + sub],     i1 = csr[j + 4 + sub];
        int i2 = csr[j + 8 + sub], i3 = csr[j + 12 + sub];
        for (int b = 1; b <= nb; ++b) {
            u32x4 q0 = *(const u32x4*)(h8 + (size_t)i0 * 256 + li * 16);
            u32x4 q1 = *(const u32x4*)(h8 + (size_t)i1 * 256 + li * 16);
            u32x4 q2 = *(const u32x4*)(h8 + (size_t)i2 * 256 + li * 16);
            u32x4 q3 = *(const u32x4*)(h8 + (size_t)i3 * 256 + li * 16);
            j += 16;
            if (b < nb) {
                i0 = csr[j + sub];     i1 = csr[j + 4 + sub];
                i2 = csr[j + 8 + sub]; i3 = csr[j + 12 + sub];
            }
            ACC16(q0); ACC16(q1); ACC16(q2); ACC16(q3);
        }
    }
    for (; j + 3 < end; j += 4) {
        int s = csr[j + sub];
        u32x4 q = *(const u32x4*)(h8 + (size_t)s * 256 + li * 16);
        ACC16(q);
    }
    if (j + sub < end) {
        int s = csr[j + sub];
        u32x4 q = *(const u32x4*)(h8 + (size_t)s * 256 + li * 16);
        ACC16(q);
    }
    // combine the 4 lane-groups: xor 16, 32
    #pragma unroll
    for (int i = 0; i < 8; i++) {
        a[i].x += __shfl_xor(a[i].x, 16, 64);
        a[i].y += __shfl_xor(a[i].y, 16, 64);
        a[i].x += __shfl_xor(a[i].x, 32, 64);
        a[i].y += __shfl_xor(a[i].y, 32, 64);
    }
    if (sub == 0) {
        u32x4 o;
        int p;
        p = __builtin_amdgcn_cvt_pk_fp8_f32(a[0].x * d, a[0].y * d, 0, false);
        p = __builtin_amdgcn_cvt_pk_fp8_f32(a[1].x * d, a[1].y * d, p, true);
        o.x = (unsigned)p;
        p = __builtin_amdgcn_cvt_pk_fp8_f32(a[2].x * d, a[2].y * d, 0, false);
        p = __builtin_amdgcn_cvt_pk_fp8_f32(a[3].x * d, a[3].y * d, p, true);
        o.y = (unsigned)p;
        p = __builtin_amdgcn_cvt_pk_fp8_f32(a[4].x * d, a[4].y * d, 0, false);
        p = __builtin_amdgcn_cvt_pk_fp8_f32(a[5].x * d, a[5].y * d, p, true);
        o.z = (unsigned)p;
        p = __builtin_amdgcn_cvt_pk_fp8_f32(a[6].x * d, a[6].y * d, 0, false);
        p = __builtin_amdgcn_cvt_pk_fp8_f32(a[7].x * d, a[7].y * d, p, true);
        o.w = (unsigned)p;
        *(u32x4*)(out + (size_t)node * 256 + li * 16) = o;
    }
}
#undef ACC16

// ---------------------------------------------------------------- MFMA GEMM 128x256, fp8 A (decoded), bf16 B
// 512 threads, 8 waves (2 wm x 4 wn of 64x64). Software-pipelined K-loop:
// LDS double-buffer; next tile's global loads issued BEFORE current tile's
// MFMAs (HBM latency hides under compute), regs written to the other buffer
// after; ONE barrier per k-step (readers of buf[cur] and writers of
// buf[cur^1] both fence on it).
// C[M,256] = relu(A8[M,K] @ B[K,256] + bias) [* dinv[row] if PRESCALE].
// If POOL: accumulate per-graph column sums into sums[] instead of writing C.
template <int K, bool PRESCALE, bool POOL>
__global__ __launch_bounds__(512) void mgemm_kernel(const unsigned char* __restrict__ A8,
                                                    const bf16* __restrict__ Bt,
                                                    const float* __restrict__ bias,
                                                    const float* __restrict__ dinv,
                                                    unsigned char* __restrict__ C8,
                                                    const int* __restrict__ batch,
                                                    float* __restrict__ sums) {
    __shared__ short As[2][128][40];   // [buf][m][k] bf16 (decoded from fp8), +8 pad
    __shared__ short Bs[2][256][40];   // [buf][n][k] bf16
    const int t    = threadIdx.x;
    const int bm   = blockIdx.x * 128;
    const int lane = t & 63;
    const int wave = t >> 6;                     // 0..7
    const int wm   = (wave >> 2) * 64;           // 0,64
    const int wn   = (wave & 3) * 64;            // 0,64,128,192
    const int m16  = lane & 15, kq = lane >> 4;
    const int arr  = t >> 2, aseg = t & 3;       // A staging: row, 8-fp8 segment
    const int grow = bm + arr;
    f32x4 acc[4][4] = {};

    auto loadA = [&](int k0) -> u32x2 {
        u32x2 v = {0u, 0u};
        if (grow < NODES) v = *(const u32x2*)(A8 + (size_t)grow * K + k0 + aseg * 8);
        return v;
    };
    auto loadB = [&](int k0, int h) -> uint4 {
        int q = t * 2 + h;                       // 0..1023
        int rr = q >> 2, seg = q & 3;
        return *(const uint4*)(Bt + (size_t)rr * K + k0 + seg * 8);
    };
    auto writeTile = [&](int buf, u32x2 va, uint4 vb0, uint4 vb1) {
        f32x2 l0 = __builtin_amdgcn_cvt_pk_f32_fp8((int)va.x, false);
        f32x2 h0 = __builtin_amdgcn_cvt_pk_f32_fp8((int)va.x, true);
        f32x2 l1 = __builtin_amdgcn_cvt_pk_f32_fp8((int)va.y, false);
        f32x2 h1 = __builtin_amdgcn_cvt_pk_f32_fp8((int)va.y, true);
        union { __hip_bfloat162 h[4]; u32x4 q; } pk;
        pk.h[0] = __float22bfloat162_rn(make_float2(l0.x, l0.y));
        pk.h[1] = __float22bfloat162_rn(make_float2(h0.x, h0.y));
        pk.h[2] = __float22bfloat162_rn(make_float2(l1.x, l1.y));
        pk.h[3] = __float22bfloat162_rn(make_float2(h1.x, h1.y));
        *(u32x4*)&As[buf][arr][aseg * 8] = pk.q;
        int q0 = t * 2, q1 = t * 2 + 1;
        *(uint4*)&Bs[buf][q0 >> 2][(q0 & 3) * 8] = vb0;
        *(uint4*)&Bs[buf][q1 >> 2][(q1 & 3) * 8] = vb1;
    };

    // prologue: stage step 0
    {
        u32x2 rA  = loadA(0);
        uint4 rB0 = loadB(0, 0);
        uint4 rB1 = loadB(0, 1);
        writeTile(0, rA, rB0, rB1);
    }
    __syncthreads();

    constexpr int NSTEP = K / 32;
    u32x2 rA;
    uint4 rB0, rB1;
    #pragma unroll
    for (int s = 0; s < NSTEP; ++s) {
        const int cur = s & 1;
        const bool more = (s + 1 < NSTEP);
        if (more) {                              // issue next-tile loads EARLY
            rA  = loadA((s + 1) * 32);
            rB0 = loadB((s + 1) * 32, 0);
            rB1 = loadB((s + 1) * 32, 1);
        }
        bf16x8 af[4], bf_[4];
        #pragma unroll
        for (int i = 0; i < 4; i++) {
            af[i]  = *(const bf16x8*)&As[cur][wm + i * 16 + m16][kq * 8];
            bf_[i] = *(const bf16x8*)&Bs[cur][wn + i * 16 + m16][kq * 8];
        }
        #pragma unroll
        for (int mt = 0; mt < 4; mt++)
            #pragma unroll
            for (int nt = 0; nt < 4; nt++)
                acc[mt][nt] = __builtin_amdgcn_mfma_f32_16x16x32_bf16(af[mt], bf_[nt],
                                                                     acc[mt][nt], 0, 0, 0);
        if (more) writeTile(cur ^ 1, rA, rB0, rB1);   // vmcnt waits land here
        __syncthreads();
    }

    // C/D layout: col = lane&15, row = (lane>>4)*4 + reg
    if (POOL) {
        bool fast = (bm + 128 <= NODES) && (batch[bm] == batch[bm + 127]);
        if (fast) {
            int g0 = batch[bm];
            #pragma unroll
            for (int nt = 0; nt < 4; nt++) {
                int colb = wn + nt * 16 + m16;
                float bv = bias[colb];
                float cs = 0.f;
                #pragma unroll
                for (int mt = 0; mt < 4; mt++)
                    #pragma unroll
                    for (int r = 0; r < 4; r++)
                        cs += fmaxf(acc[mt][nt][r] + bv, 0.f);
                cs += __shfl_xor(cs, 16, 64);     // reduce over kq
                cs += __shfl_xor(cs, 32, 64);
                if (kq == 0) atomicAdd(&sums[g0 * 256 + colb], cs);
            }
        } else {
            #pragma unroll
            for (int mt = 0; mt < 4; mt++) {
                #pragma unroll
                for (int r = 0; r < 4; r++) {
                    int row = bm + wm + mt * 16 + kq * 4 + r;
                    if (row >= NODES) continue;
                    int g = batch[row];
                    #pragma unroll
                    for (int nt = 0; nt < 4; nt++) {
                        int colb = wn + nt * 16 + m16;
                        float v = fmaxf(acc[mt][nt][r] + bias[colb], 0.f);
                        atomicAdd(&sums[g * 256 + colb], v);
                    }
                }
            }
        }
    } else {
        #pragma unroll
        for (int mt = 0; mt < 4; mt++) {
            #pragma unroll
            for (int r = 0; r < 4; r++) {
                int row = bm + wm + mt * 16 + kq * 4 + r;
                if (row >= NODES) continue;
                float sc = PRESCALE ? dinv[row] : 1.f;
                #pragma unroll
                for (int nt = 0; nt < 4; nt++) {
                    int colb = wn + nt * 16 + m16;
                    float v = fmaxf(acc[mt][nt][r] + bias[colb], 0.f) * sc;
                    int pkd = __builtin_amdgcn_cvt_pk_fp8_f32(v, v, 0, false);
                    C8[(size_t)row * 256 + colb] = (unsigned char)(pkd & 0xff);
                }
            }
        }
    }
}

// ---------------------------------------------------------------- pooled @ Wl + bl
__global__ void final_kernel(const float* __restrict__ sums, const int* __restrict__ batch,
                             const float* __restrict__ Wl, const float* __restrict__ bl,
                             float* __restrict__ out) {
    int g = blockIdx.x;
    int l = threadIdx.x;
    int lo = 0, hi = NODES;
    while (lo < hi) { int m = (lo + hi) >> 1; if (batch[m] < g) lo = m + 1; else hi = m; }
    int lb = lo;
    lo = lb; hi = NODES;
    while (lo < hi) { int m = (lo + hi) >> 1; if (batch[m] <= g) lo = m + 1; else hi = m; }
    int cnt = lo - lb;
    float inv = 1.f / fmaxf((float)cnt, 1.f);
    float a0 = 0.f, a1 = 0.f;
    for (int k = l; k < 256; k += 64) {
        float p = sums[g * 256 + k] * inv;
        a0 += p * Wl[k * 2 + 0];
        a1 += p * Wl[k * 2 + 1];
    }
    for (int off = 32; off > 0; off >>= 1) {
        a0 += __shfl_down(a0, off, 64);
        a1 += __shfl_down(a1, off, 64);
    }
    if (l == 0) {
        out[g * 2 + 0] = a0 + bl[0];
        out[g * 2 + 1] = a1 + bl[1];
    }
}

// ---------------------------------------------------------------- launch
extern "C" void kernel_launch(void* const* d_in, const int* in_sizes, int n_in,
                              void* d_out, int out_size, void* d_ws, size_t ws_size,
                              hipStream_t stream) {
    const float* x    = (const float*)d_in[0];
    const int*   ei   = (const int*)d_in[1];
    const int*   bat  = (const int*)d_in[2];
    const float* W1   = (const float*)d_in[3];
    const float* b1   = (const float*)d_in[4];
    const float* W2   = (const float*)d_in[5];
    const float* b2   = (const float*)d_in[6];
    const float* Wl   = (const float*)d_in[7];
    const float* bl   = (const float*)d_in[8];
    float*       out  = (float*)d_out;
    const int* erow = ei;           // edge_index[0] = source
    const int* ecol = ei + EDGES;   // edge_index[1] = target

    char* p = (char*)d_ws;
    auto take = [&](size_t bytes) {
        char* r = p;
        p += (bytes + 255) & ~(size_t)255;
        return r;
    };
    float* dinv   = (float*)take((size_t)NODES * 4);
    int*   rowptr = (int*)  take((size_t)(NODES + 1) * 4);
    int*   gcnt   = (int*)  take((size_t)NBUCK * 4);
    int*   csr    = (int*)  take((size_t)ETOT * 4);
    float* sums   = (float*)take((size_t)NGRAPH * HDIM * 4);
    bf16*  W1t    = (bf16*) take((size_t)128 * 256 * 2);
    bf16*  W2t    = (bf16*) take((size_t)256 * 256 * 2);
    char*  reg1   = (char*) take((size_t)NODES * HDIM * 1);   // x8 (12.8) -> h1f8 (25.6)
    char*  reg2   = (char*) take((size_t)NODES * HDIM * 1);   // aggbuf1 (12.8) -> aggbuf2 (25.6)
    char*  reg3   = (char*) take((size_t)NODES * HDIM * 1);   // recs (19.6)
    unsigned char* x8      = (unsigned char*)reg1; // dead after agg1
    unsigned char* h1f8    = (unsigned char*)reg1; // born mgemm1, dead after agg2
    unsigned char* aggbuf1 = (unsigned char*)reg2; // born agg1, dead after mgemm1
    unsigned char* aggbuf2 = (unsigned char*)reg2; // born agg2, dead after mgemm2
    unsigned*      recs    = (unsigned*)reg3;      // dead after build

    hipMemsetAsync(sums, 0, (size_t)NGRAPH * HDIM * 4, stream);
    hipMemsetAsync(gcnt, 0, (size_t)NBUCK * 4, stream);
    wcast_kernel<<<(128 * 256 + 256 * 256 + 255) / 256, 256, 0, stream>>>(W1, W2, W1t, W2t);

    fillp1_kernel<<<(ETOT + 8191) / 8192, 1024, 0, stream>>>(erow, ecol, gcnt, recs);
    build_kernel <<<NBUCK, 256, 0, stream>>>(recs, gcnt, rowptr, dinv, csr);

    // xcast needs dinv -> after build (standalone: full-grid streaming)
    xcast_kernel<<<(NODES * 128 / 4 + 255) / 256, 256, 0, stream>>>(x, dinv, x8);

    const int AGG_BLOCKS = ((size_t)NODES * 64 + 255) / 256;  // 1 node per wave
    agg1_kernel<<<AGG_BLOCKS, 256, 0, stream>>>(x8, rowptr, csr, dinv, aggbuf1);

    const int MB = (NODES + 127) / 128;               // 782 (one block per 128 rows, full 256 cols)
    mgemm_kernel<128, true,  false><<<MB, 512, 0, stream>>>(aggbuf1, W1t, b1, dinv, h1f8,
                                                            nullptr, nullptr);

    agg2_kernel<<<AGG_BLOCKS, 256, 0, stream>>>(h1f8, rowptr, csr, dinv, aggbuf2);

    // mgemm2 pools directly into sums (h2 never materialized)
    mgemm_kernel<256, false, true ><<<MB, 512, 0, stream>>>(aggbuf2, W2t, b2, nullptr, nullptr,
                                                            bat, sums);

    final_kernel<<<NGRAPH, 64, 0, stream>>>(sums, bat, Wl, bl, out);
}